// Round 1
// baseline (2943.384 us; speedup 1.0000x reference)
//
#include <hip/hip_runtime.h>
#include <stdint.h>

typedef unsigned short u16;
typedef __attribute__((ext_vector_type(8))) short bf8_t;   // 8 x bf16 (guide-verified frag type)
typedef __attribute__((ext_vector_type(4))) float f4_t;

#define DEV static __device__ __forceinline__
#define MFMA16(a, b, c) __builtin_amdgcn_mfma_f32_16x16x32_bf16((a), (b), (c), 0, 0, 0)
#define GLDS(gp, lp) __builtin_amdgcn_global_load_lds((const __attribute__((address_space(1))) void*)(gp), \
                                                      (__attribute__((address_space(3))) void*)(lp), 16, 0, 0)

DEV u16 f2bf(float f) {  // RNE float->bf16, no hip_bf16 header dependency
  union { float f; uint32_t u; } x; x.f = f;
  uint32_t r = x.u + 0x7FFFu + ((x.u >> 16) & 1u);
  return (u16)(r >> 16);
}

// ---------------------------------------------------------------- transpose
// W [K][N] f32  ->  WT [N][K] bf16   (32x32 LDS tiles, K,N multiples of 32)
__global__ __launch_bounds__(256) void transpose_k(const float* __restrict__ W, u16* __restrict__ WT,
                                                   int K, int N) {
  __shared__ float tile[32][33];
  const int n0 = blockIdx.x * 32, k0 = blockIdx.y * 32;
  const int tx = threadIdx.x & 31, ty = threadIdx.x >> 5;  // 8 rows of 32
  #pragma unroll
  for (int i = 0; i < 32; i += 8)
    tile[ty + i][tx] = W[(long)(k0 + ty + i) * N + n0 + tx];
  __syncthreads();
  #pragma unroll
  for (int i = 0; i < 32; i += 8)
    WT[(long)(n0 + ty + i) * K + k0 + tx] = f2bf(tile[tx][ty + i]);
}

// ---------------------------------------------------------------- GEMM (m97 structure)
// C[M][N] = A[M][K](bf16) * BT[N][K]^T(bf16) + bias, with fused epilogues.
enum { EPI_F32 = 0, EPI_GATE = 1, EPI_GELU = 2 };

template <int EPI>
__global__ __launch_bounds__(256)
void gemm_bt(const u16* __restrict__ A, const u16* __restrict__ BT, const float* __restrict__ bias,
             float* outF, u16* outB, const float* gate, const float* res, int M, int N, int K) {
  __shared__ u16 sA[128 * 32];
  __shared__ u16 sB[128 * 32];
  const int tid = threadIdx.x, lane = tid & 63, wid = tid >> 6;
  const long rowBase = (long)blockIdx.x * 128;
  const long colBase = (long)blockIdx.y * 128;
  const int wr = (wid >> 1) * 64, wc = (wid & 1) * 64;
  const int fr = lane & 15, kg = (lane >> 4) * 8;

  const f4_t zero = {0.0f, 0.0f, 0.0f, 0.0f};
  f4_t acc[4][4];
  #pragma unroll
  for (int i = 0; i < 4; ++i)
    #pragma unroll
    for (int j = 0; j < 4; ++j) acc[i][j] = zero;

  // staging geometry: 8 chunks of 16 rows; wave w stages chunks 2w, 2w+1; lane -> (row, 16B)
  const int c0 = wid * 2;
  const int sr = lane >> 2, scol = (lane & 3) * 8;
  const u16* Ag0 = A + (rowBase + c0 * 16 + sr) * (long)K + scol;
  const u16* Ag1 = A + (rowBase + c0 * 16 + 16 + sr) * (long)K + scol;
  const u16* Bg0 = BT + (colBase + c0 * 16 + sr) * (long)K + scol;
  const u16* Bg1 = BT + (colBase + c0 * 16 + 16 + sr) * (long)K + scol;
  u16* lA0 = &sA[(c0 * 16) * 32];
  u16* lA1 = &sA[(c0 * 16 + 16) * 32];
  u16* lB0 = &sB[(c0 * 16) * 32];
  u16* lB1 = &sB[(c0 * 16 + 16) * 32];

  for (int k0 = 0; k0 < K; k0 += 32) {
    GLDS(Ag0 + k0, lA0);
    GLDS(Ag1 + k0, lA1);
    GLDS(Bg0 + k0, lB0);
    GLDS(Bg1 + k0, lB1);
    __syncthreads();
    bf8_t af[4], bfv[4];
    #pragma unroll
    for (int m = 0; m < 4; ++m) af[m] = *(const bf8_t*)&sA[(wr + m * 16 + fr) * 32 + kg];
    #pragma unroll
    for (int n = 0; n < 4; ++n) bfv[n] = *(const bf8_t*)&sB[(wc + n * 16 + fr) * 32 + kg];
    #pragma unroll
    for (int m = 0; m < 4; ++m)
      #pragma unroll
      for (int n = 0; n < 4; ++n) acc[m][n] = MFMA16(af[m], bfv[n], acc[m][n]);
    __syncthreads();
  }

  const int r0 = (lane >> 4) * 4;
  #pragma unroll
  for (int m = 0; m < 4; ++m) {
    #pragma unroll
    for (int n = 0; n < 4; ++n) {
      const long col = colBase + wc + n * 16 + fr;
      const float bv = bias[col];
      #pragma unroll
      for (int j = 0; j < 4; ++j) {
        const long row = rowBase + wr + m * 16 + r0 + j;
        float v = acc[m][n][j] + bv;
        if (EPI == EPI_F32) {
          outF[row * N + col] = v;
        } else if (EPI == EPI_GATE) {
          const int b = (int)(row >> 10);  // S = 1024
          const float g = gate[(long)b * 6144 + col];
          outF[row * N + col] = v * g + res[row * N + col];
        } else {  // tanh-GELU -> bf16
          const float t = 0.7978845608028654f * (v + 0.044715f * v * v * v);
          const float e = __expf(2.0f * t);
          const float th = 1.0f - 2.0f / (e + 1.0f);
          outB[row * N + col] = f2bf(0.5f * v * (1.0f + th));
        }
      }
    }
  }
}

// ---------------------------------------------------------------- LayerNorm + adaLN modulation -> bf16
__global__ __launch_bounds__(256)
void ln_mod(const float* __restrict__ h, const float* __restrict__ gamma, const float* __restrict__ beta,
            const float* shp, const float* scp, int bstride, u16* __restrict__ xb) {
  __shared__ float red[8];
  const int row = blockIdx.x;
  const int b = row >> 10;
  const int t = threadIdx.x;
  const float* hp = h + (long)row * 1024;
  float4 x = *(const float4*)&hp[t * 4];
  float s = x.x + x.y + x.z + x.w;
  #pragma unroll
  for (int o = 32; o > 0; o >>= 1) s += __shfl_down(s, o);
  const int lane = t & 63, wid = t >> 6;
  if (lane == 0) red[wid] = s;
  __syncthreads();
  const float mean = (red[0] + red[1] + red[2] + red[3]) * 0.0009765625f;
  const float d0 = x.x - mean, d1 = x.y - mean, d2 = x.z - mean, d3 = x.w - mean;
  float vs = d0 * d0 + d1 * d1 + d2 * d2 + d3 * d3;
  #pragma unroll
  for (int o = 32; o > 0; o >>= 1) vs += __shfl_down(vs, o);
  if (lane == 0) red[4 + wid] = vs;
  __syncthreads();
  const float var = (red[4] + red[5] + red[6] + red[7]) * 0.0009765625f;
  const float inv = rsqrtf(var + 1e-5f);
  const int d = t * 4;
  const float4 gg = *(const float4*)&gamma[d];
  const float4 bb = *(const float4*)&beta[d];
  const float4 sh = *(const float4*)&shp[(long)b * bstride + d];
  const float4 sc = *(const float4*)&scp[(long)b * bstride + d];
  union { u16 u[4]; uint2 v; } pk;
  pk.u[0] = f2bf((d0 * inv * gg.x + bb.x) * (1.0f + sc.x) + sh.x);
  pk.u[1] = f2bf((d1 * inv * gg.y + bb.y) * (1.0f + sc.y) + sh.y);
  pk.u[2] = f2bf((d2 * inv * gg.z + bb.z) * (1.0f + sc.z) + sh.z);
  pk.u[3] = f2bf((d3 * inv * gg.w + bb.w) * (1.0f + sc.w) + sh.w);
  *(uint2*)&xb[(long)row * 1024 + d] = pk.v;
}

// ---------------------------------------------------------------- RoPE split q/k/v -> bf16 [B][H][S][64]
__global__ __launch_bounds__(256)
void rope_split(const float* __restrict__ qkv, const float* __restrict__ ct, const float* __restrict__ st,
                u16* __restrict__ qb, u16* __restrict__ kb, u16* __restrict__ vb) {
  const int row = blockIdx.x;  // b*1024 + s
  const int b = row >> 10, s = row & 1023;
  const float* rp = qkv + (long)row * 3072;
  const int t = threadIdx.x;
  #pragma unroll
  for (int which = 0; which < 2; ++which) {
    const float* xp = rp + which * 1024;
    u16* op = which ? kb : qb;
    #pragma unroll
    for (int j = 0; j < 2; ++j) {
      const int p = t + j * 256;          // pair index 0..511
      const int h = p >> 5, i = p & 31;
      const float xe = xp[h * 64 + 2 * i], xo = xp[h * 64 + 2 * i + 1];
      const float c = ct[s * 32 + i], sn = st[s * 32 + i];
      const long base = (((long)(b * 16 + h)) * 1024 + s) * 64 + 2 * i;
      op[base] = f2bf(xe * c - xo * sn);
      op[base + 1] = f2bf(xe * sn + xo * c);
    }
  }
  const float* vp = rp + 2048;
  #pragma unroll
  for (int j = 0; j < 4; ++j) {
    const int d = t + j * 256;
    const int h = d >> 6, dd = d & 63;
    vb[(((long)(b * 16 + h)) * 1024 + s) * 64 + dd] = f2bf(vp[d]);
  }
}

// ---------------------------------------------------------------- fused attention (per b, h, 32 q-rows)
__global__ __launch_bounds__(256)
void attn_k(const u16* __restrict__ qb, const u16* __restrict__ kb, const u16* __restrict__ vb,
            const float* __restrict__ amask, u16* __restrict__ ob) {
  __shared__ float sS[32 * 1032];  // padded row stride vs bank conflicts
  __shared__ u16 sVT[64 * 64];
  __shared__ float sInv[32];
  const int q0 = blockIdx.x * 32;
  const int h = blockIdx.y, b = blockIdx.z;
  const long bh = b * 16 + h;
  const u16* Q = qb + (bh * 1024 + q0) * 64;
  const u16* Kp = kb + bh * 1024 * 64;
  const u16* Vp = vb + bh * 1024 * 64;
  const int tid = threadIdx.x, lane = tid & 63, wid = tid >> 6;
  const int fr = lane & 15, kg = (lane >> 4) * 8, r0 = (lane >> 4) * 4;
  const f4_t zero = {0.0f, 0.0f, 0.0f, 0.0f};

  bf8_t qf[2][2];
  #pragma unroll
  for (int m = 0; m < 2; ++m)
    #pragma unroll
    for (int ks = 0; ks < 2; ++ks)
      qf[m][ks] = *(const bf8_t*)&Q[(m * 16 + fr) * 64 + ks * 32 + kg];

  // phase 1: scores  (wave w owns k-cols [256w, 256w+256))
  for (int nf = 0; nf < 16; ++nf) {
    const int c = wid * 256 + nf * 16;
    const u16* kp = &Kp[(long)(c + fr) * 64 + kg];
    bf8_t kf0 = *(const bf8_t*)kp;
    bf8_t kf1 = *(const bf8_t*)(kp + 32);
    f4_t s0 = zero, s1 = zero;
    s0 = MFMA16(qf[0][0], kf0, s0);
    s0 = MFMA16(qf[0][1], kf1, s0);
    s1 = MFMA16(qf[1][0], kf0, s1);
    s1 = MFMA16(qf[1][1], kf1, s1);
    const float am = amask[(long)b * 1024 + c + fr];
    const float madd = (1.0f - am) * -3.402823466e38f;
    #pragma unroll
    for (int j = 0; j < 4; ++j) {
      sS[(r0 + j) * 1032 + c + fr] = s0[j] * 0.125f + madd;
      sS[(16 + r0 + j) * 1032 + c + fr] = s1[j] * 0.125f + madd;
    }
  }
  __syncthreads();

  // phase 2: softmax in place (8 lanes per row)
  {
    const int row = wid * 8 + (lane >> 3);
    const int l8 = lane & 7;
    float* rp = &sS[row * 1032 + l8 * 128];
    float mx = -3.402823466e38f;
    for (int j = 0; j < 32; ++j) {
      f4_t v = *(const f4_t*)&rp[j * 4];
      mx = fmaxf(mx, fmaxf(fmaxf(v[0], v[1]), fmaxf(v[2], v[3])));
    }
    #pragma unroll
    for (int o = 1; o < 8; o <<= 1) mx = fmaxf(mx, __shfl_xor(mx, o));
    float sum = 0.0f;
    for (int j = 0; j < 32; ++j) {
      f4_t v = *(const f4_t*)&rp[j * 4];
      f4_t e;
      e[0] = __expf(v[0] - mx); e[1] = __expf(v[1] - mx);
      e[2] = __expf(v[2] - mx); e[3] = __expf(v[3] - mx);
      *(f4_t*)&rp[j * 4] = e;
      sum += e[0] + e[1] + e[2] + e[3];
    }
    #pragma unroll
    for (int o = 1; o < 8; o <<= 1) sum += __shfl_xor(sum, o);
    if (l8 == 0) sInv[row] = 1.0f / sum;
  }

  // phase 3: PV (wave w owns d-cols [16w, 16w+16))
  f4_t oacc[2];
  oacc[0] = zero; oacc[1] = zero;
  const int col16 = wid * 16;
  for (int kc = 0; kc < 1024; kc += 64) {
    __syncthreads();
    #pragma unroll
    for (int it = 0; it < 2; ++it) {
      const int kk = (tid >> 3) + it * 32;
      const int d0 = (tid & 7) * 8;
      union { uint4 v; u16 u[8]; } un;
      un.v = *(const uint4*)&Vp[(long)(kc + kk) * 64 + d0];
      #pragma unroll
      for (int e = 0; e < 8; ++e) sVT[(d0 + e) * 64 + kk] = un.u[e];
    }
    __syncthreads();
    #pragma unroll
    for (int ks = 0; ks < 2; ++ks) {
      bf8_t vf = *(const bf8_t*)&sVT[(col16 + fr) * 64 + ks * 32 + kg];
      #pragma unroll
      for (int m = 0; m < 2; ++m) {
        const float* pp = &sS[(m * 16 + fr) * 1032 + kc + ks * 32 + kg];
        f4_t p0 = *(const f4_t*)pp;
        f4_t p1 = *(const f4_t*)(pp + 4);
        bf8_t pa;
        pa[0] = (short)f2bf(p0[0]); pa[1] = (short)f2bf(p0[1]);
        pa[2] = (short)f2bf(p0[2]); pa[3] = (short)f2bf(p0[3]);
        pa[4] = (short)f2bf(p1[0]); pa[5] = (short)f2bf(p1[1]);
        pa[6] = (short)f2bf(p1[2]); pa[7] = (short)f2bf(p1[3]);
        oacc[m] = MFMA16(pa, vf, oacc[m]);
      }
    }
  }
  #pragma unroll
  for (int m = 0; m < 2; ++m) {
    #pragma unroll
    for (int j = 0; j < 4; ++j) {
      const int r32 = m * 16 + r0 + j;
      const float val = oacc[m][j] * sInv[r32];
      const long row = (long)b * 1024 + q0 + r32;
      ob[row * 1024 + h * 64 + col16 + fr] = f2bf(val);
    }
  }
}

// ---------------------------------------------------------------- small kernels
__global__ void rope_tables(float* ct, float* st) {
  const int i = blockIdx.x * 256 + threadIdx.x;  // S*32 = 32768
  const int s = i >> 5, k = i & 31;
  const float freq = __expf(-9.210340371976184f * (float)(2 * k) / 64.0f);
  const float a = (float)s * freq;
  ct[i] = cosf(a);
  st[i] = sinf(a);
}

__global__ void init_hs(const float* __restrict__ e, const float* __restrict__ wpe, float* __restrict__ hs) {
  const long i = (long)blockIdx.x * 256 + threadIdx.x;  // 524288 float4s
  float4 a = ((const float4*)e)[i];
  const float4 w = ((const float4*)wpe)[i & 262143];
  a.x += w.x; a.y += w.y; a.z += w.z; a.w += w.w;
  ((float4*)hs)[i] = a;
}

__global__ void time_proj_k(const float* __restrict__ ts, float* __restrict__ tproj) {
  const int j = blockIdx.x * 256 + threadIdx.x;  // 0..511
  const int b = blockIdx.y;
  const float tf = __expf(-9.210340371976184f * (float)(j & 255) / 256.0f);
  const float a = ts[b] * tf * 1000.0f;
  tproj[b * 512 + j] = (j < 256) ? cosf(a) : sinf(a);
}

__global__ void time_mlp1(const float* __restrict__ tproj, const float* __restrict__ w1,
                          const float* __restrict__ b1, float* __restrict__ h1) {
  const int d = blockIdx.x * 256 + threadIdx.x;
  const int b = blockIdx.y;
  float acc = b1[d];
  for (int j = 0; j < 512; ++j) acc += tproj[b * 512 + j] * w1[(long)j * 1024 + d];
  h1[b * 1024 + d] = acc / (1.0f + __expf(-acc));  // silu
}

__global__ void time_mlp2(const float* __restrict__ h1, const float* __restrict__ w2,
                          const float* __restrict__ b2, float* __restrict__ emb) {
  const int d = blockIdx.x * 256 + threadIdx.x;
  const int b = blockIdx.y;
  float acc = b2[d];
  for (int j = 0; j < 1024; ++j) acc += h1[b * 1024 + j] * w2[(long)j * 1024 + d];
  emb[b * 1024 + d] = acc;
}

__global__ void silu_k(const float* __restrict__ in, float* __restrict__ out, int n) {
  const int i = blockIdx.x * 256 + threadIdx.x;
  if (i < n) { const float v = in[i]; out[i] = v / (1.0f + __expf(-v)); }
}

__global__ void adaln_k(const float* __restrict__ se, const float* __restrict__ aw,
                        const float* __restrict__ ab, float* __restrict__ adaln) {
  const int j = blockIdx.x * 256 + threadIdx.x;  // 0..6143
  const int b = blockIdx.y;
  float acc = ab[j];
  for (int k = 0; k < 1024; ++k) acc += se[b * 1024 + k] * aw[(long)k * 6144 + j];
  adaln[b * 6144 + j] = acc;
}

// modAll[l][b][slot][d] = sst[l][slot][d] + adaln[b][slot*1024+d];   fmod[b][i][d] = fsst[i][d] + emb[b][d]
__global__ void build_mods(const float* __restrict__ sst, const float* __restrict__ adaln,
                           const float* __restrict__ fsst, const float* __restrict__ emb,
                           float* __restrict__ modAll, float* __restrict__ fmod) {
  const int i = blockIdx.x * 256 + threadIdx.x;
  if (i < 98304) {
    const int d = i & 1023;
    const int rest = i >> 10;
    const int slot = rest % 6;
    const int t2 = rest / 6;
    const int bb = t2 & 1, l = t2 >> 1;
    modAll[i] = sst[(long)(l * 6 + slot) * 1024 + d] + adaln[bb * 6144 + slot * 1024 + d];
  } else if (i < 98304 + 4096) {
    const int j = i - 98304;
    const int d = j & 1023;
    const int slot = (j >> 10) & 1;
    const int bb = j >> 11;
    fmod[j] = fsst[slot * 1024 + d] + emb[bb * 1024 + d];
  }
}

// ---------------------------------------------------------------- launch
extern "C" void kernel_launch(void* const* d_in, const int* in_sizes, int n_in,
                              void* d_out, int out_size, void* d_ws, size_t ws_size,
                              hipStream_t stream) {
  const float* inp_emb = (const float*)d_in[0];
  const float* amask  = (const float*)d_in[1];
  const float* tstep  = (const float*)d_in[2];
  const float* wpe    = (const float*)d_in[3];
  const float* ln1_g  = (const float*)d_in[4];
  const float* ln1_b  = (const float*)d_in[5];
  const float* attn_w = (const float*)d_in[6];
  const float* attn_b = (const float*)d_in[7];
  const float* projw  = (const float*)d_in[8];
  const float* projb  = (const float*)d_in[9];
  const float* ln2_g  = (const float*)d_in[10];
  const float* ln2_b  = (const float*)d_in[11];
  const float* fcw    = (const float*)d_in[12];
  const float* fcb    = (const float*)d_in[13];
  const float* pw2    = (const float*)d_in[14];
  const float* pb2    = (const float*)d_in[15];
  const float* sst    = (const float*)d_in[16];
  const float* te_w1  = (const float*)d_in[17];
  const float* te_b1  = (const float*)d_in[18];
  const float* te_w2  = (const float*)d_in[19];
  const float* te_b2  = (const float*)d_in[20];
  const float* ada_w  = (const float*)d_in[21];
  const float* ada_b  = (const float*)d_in[22];
  const float* lnf_g  = (const float*)d_in[23];
  const float* lnf_b  = (const float*)d_in[24];
  const float* fsst   = (const float*)d_in[25];
  const float* out_w  = (const float*)d_in[26];
  const float* out_b  = (const float*)d_in[27];
  float* out = (float*)d_out;
  (void)in_sizes; (void)n_in; (void)out_size; (void)ws_size;

  char* wsb = (char*)d_ws;
  size_t off = 0;
  auto alloc = [&](size_t bytes) -> void* {
    void* p = wsb + off;
    off += (bytes + 255) & ~(size_t)255;
    return p;
  };
  u16* wtA = (u16*)alloc(3072ll * 1024 * 2);   // per-layer attn_w^T bf16
  u16* wtP = (u16*)alloc(1024ll * 1024 * 2);   // projw^T
  u16* wtF = (u16*)alloc(4096ll * 1024 * 2);   // fcw^T
  u16* wtQ = (u16*)alloc(1024ll * 4096 * 2);   // pw2^T
  u16* wtO = (u16*)alloc(1024ll * 1024 * 2);   // out_w^T
  float* hs   = (float*)alloc(2048ll * 1024 * 4);
  float* qkv  = (float*)alloc(2048ll * 3072 * 4);
  u16*   ffb  = (u16*)qkv;                     // alias: FF activations live where qkv did
  u16* xb = (u16*)alloc(2048ll * 1024 * 2);
  u16* qb = (u16*)alloc(2048ll * 1024 * 2);
  u16* kb = (u16*)alloc(2048ll * 1024 * 2);
  u16* vb = (u16*)alloc(2048ll * 1024 * 2);
  u16* ob = (u16*)alloc(2048ll * 1024 * 2);
  float* ct    = (float*)alloc(32768 * 4);
  float* st    = (float*)alloc(32768 * 4);
  float* tproj = (float*)alloc(2 * 512 * 4);
  float* h1    = (float*)alloc(2 * 1024 * 4);
  float* emb   = (float*)alloc(2 * 1024 * 4);
  float* se    = (float*)alloc(2 * 1024 * 4);
  float* adaln = (float*)alloc(2 * 6144 * 4);
  float* modAll = (float*)alloc(8ll * 2 * 6 * 1024 * 4);
  float* fmod   = (float*)alloc(2 * 2 * 1024 * 4);

  rope_tables<<<128, 256, 0, stream>>>(ct, st);
  init_hs<<<2048, 256, 0, stream>>>(inp_emb, wpe, hs);
  time_proj_k<<<dim3(2, 2), 256, 0, stream>>>(tstep, tproj);
  time_mlp1<<<dim3(4, 2), 256, 0, stream>>>(tproj, te_w1, te_b1, h1);
  time_mlp2<<<dim3(4, 2), 256, 0, stream>>>(h1, te_w2, te_b2, emb);
  silu_k<<<8, 256, 0, stream>>>(emb, se, 2048);
  adaln_k<<<dim3(24, 2), 256, 0, stream>>>(se, ada_w, ada_b, adaln);
  build_mods<<<400, 256, 0, stream>>>(sst, adaln, fsst, emb, modAll, fmod);
  transpose_k<<<dim3(32, 32), 256, 0, stream>>>(out_w, wtO, 1024, 1024);

  for (int l = 0; l < 8; ++l) {
    const float* ml = modAll + (long)l * 12288;
    transpose_k<<<dim3(96, 32), 256, 0, stream>>>(attn_w + (long)l * 1024 * 3072, wtA, 1024, 3072);
    transpose_k<<<dim3(32, 32), 256, 0, stream>>>(projw + (long)l * 1024 * 1024, wtP, 1024, 1024);
    transpose_k<<<dim3(128, 32), 256, 0, stream>>>(fcw + (long)l * 1024 * 4096, wtF, 1024, 4096);
    transpose_k<<<dim3(32, 128), 256, 0, stream>>>(pw2 + (long)l * 4096 * 1024, wtQ, 4096, 1024);

    ln_mod<<<2048, 256, 0, stream>>>(hs, ln1_g + l * 1024, ln1_b + l * 1024,
                                     ml + 0 * 1024, ml + 1 * 1024, 6144, xb);
    gemm_bt<EPI_F32><<<dim3(16, 24), 256, 0, stream>>>(xb, wtA, attn_b + l * 3072,
                                                       qkv, nullptr, nullptr, nullptr, 2048, 3072, 1024);
    rope_split<<<2048, 256, 0, stream>>>(qkv, ct, st, qb, kb, vb);
    attn_k<<<dim3(32, 16, 2), 256, 0, stream>>>(qb, kb, vb, amask, ob);
    gemm_bt<EPI_GATE><<<dim3(16, 8), 256, 0, stream>>>(ob, wtP, projb + l * 1024,
                                                       hs, nullptr, ml + 2 * 1024, hs, 2048, 1024, 1024);
    ln_mod<<<2048, 256, 0, stream>>>(hs, ln2_g + l * 1024, ln2_b + l * 1024,
                                     ml + 3 * 1024, ml + 4 * 1024, 6144, xb);
    gemm_bt<EPI_GELU><<<dim3(16, 32), 256, 0, stream>>>(xb, wtF, fcb + l * 4096,
                                                        nullptr, ffb, nullptr, nullptr, 2048, 4096, 1024);
    gemm_bt<EPI_GATE><<<dim3(16, 8), 256, 0, stream>>>(ffb, wtQ, pb2 + l * 1024,
                                                       hs, nullptr, ml + 5 * 1024, hs, 2048, 1024, 4096);
  }

  ln_mod<<<2048, 256, 0, stream>>>(hs, lnf_g, lnf_b, fmod + 0, fmod + 1024, 2048, xb);
  gemm_bt<EPI_F32><<<dim3(16, 8), 256, 0, stream>>>(xb, wtO, out_b,
                                                    out, nullptr, nullptr, nullptr, 2048, 1024, 1024);
}

// Round 2
// 2258.667 us; speedup vs baseline: 1.3032x; 1.3032x over previous
//
#include <hip/hip_runtime.h>
#include <stdint.h>

typedef unsigned short u16;
typedef __attribute__((ext_vector_type(8))) short bf8_t;   // 8 x bf16
typedef __attribute__((ext_vector_type(4))) float f4_t;

#define DEV static __device__ __forceinline__
#define MFMA16(a, b, c) __builtin_amdgcn_mfma_f32_16x16x32_bf16((a), (b), (c), 0, 0, 0)
#define GLDS(gp, lp) __builtin_amdgcn_global_load_lds((const __attribute__((address_space(1))) void*)(gp), \
                                                      (__attribute__((address_space(3))) void*)(lp), 16, 0, 0)

DEV u16 f2bf(float f) {  // RNE float->bf16
  union { float f; uint32_t u; } x; x.f = f;
  uint32_t r = x.u + 0x7FFFu + ((x.u >> 16) & 1u);
  return (u16)(r >> 16);
}

// ---------------------------------------------------------------- transpose
// W [K][N] f32  ->  WT [N][K] bf16
__global__ __launch_bounds__(256) void transpose_k(const float* __restrict__ W, u16* __restrict__ WT,
                                                   int K, int N) {
  __shared__ float tile[32][33];
  const int n0 = blockIdx.x * 32, k0 = blockIdx.y * 32;
  const int tx = threadIdx.x & 31, ty = threadIdx.x >> 5;
  #pragma unroll
  for (int i = 0; i < 32; i += 8)
    tile[ty + i][tx] = W[(long)(k0 + ty + i) * N + n0 + tx];
  __syncthreads();
  #pragma unroll
  for (int i = 0; i < 32; i += 8)
    WT[(long)(n0 + ty + i) * K + k0 + tx] = f2bf(tile[tx][ty + i]);
}

// ---------------------------------------------------------------- GEMM (m97 structure, tile-templated)
enum { EPI_F32 = 0, EPI_GATE = 1, EPI_GELU = 2 };

template <int BM, int EPI>
__global__ __launch_bounds__(256)
void gemm_bt(const u16* __restrict__ A, const u16* __restrict__ BT, const float* __restrict__ bias,
             float* outF, u16* outB, const float* gate, const float* res, int M, int N, int K) {
  constexpr int MI = BM / 32;
  __shared__ u16 sA[BM * 32];
  __shared__ u16 sB[128 * 32];
  const int tid = threadIdx.x, lane = tid & 63, wid = tid >> 6;
  const long rowBase = (long)blockIdx.x * BM;
  const long colBase = (long)blockIdx.y * 128;
  const int wr = (wid >> 1) * (BM / 2), wc = (wid & 1) * 64;
  const int fr = lane & 15, kg = (lane >> 4) * 8;

  const f4_t zero = {0.0f, 0.0f, 0.0f, 0.0f};
  f4_t acc[MI][4];
  #pragma unroll
  for (int i = 0; i < MI; ++i)
    #pragma unroll
    for (int j = 0; j < 4; ++j) acc[i][j] = zero;

  const int sr = lane >> 2, scol = (lane & 3) * 8;
  const int c0 = wid * 2;
  const u16 *Ag0, *Ag1 = nullptr, *Bg0, *Bg1;
  u16 *lA0, *lA1 = nullptr, *lB0, *lB1;
  if constexpr (BM == 128) {
    Ag0 = A + (rowBase + c0 * 16 + sr) * (long)K + scol;
    Ag1 = A + (rowBase + c0 * 16 + 16 + sr) * (long)K + scol;
    lA0 = &sA[(c0 * 16) * 32];
    lA1 = &sA[(c0 * 16 + 16) * 32];
  } else {  // BM == 64: wave stages one 16-row A chunk
    Ag0 = A + (rowBase + wid * 16 + sr) * (long)K + scol;
    lA0 = &sA[(wid * 16) * 32];
  }
  Bg0 = BT + (colBase + c0 * 16 + sr) * (long)K + scol;
  Bg1 = BT + (colBase + c0 * 16 + 16 + sr) * (long)K + scol;
  lB0 = &sB[(c0 * 16) * 32];
  lB1 = &sB[(c0 * 16 + 16) * 32];

  for (int k0 = 0; k0 < K; k0 += 32) {
    GLDS(Ag0 + k0, lA0);
    if constexpr (BM == 128) GLDS(Ag1 + k0, lA1);
    GLDS(Bg0 + k0, lB0);
    GLDS(Bg1 + k0, lB1);
    __syncthreads();
    bf8_t af[MI], bfv[4];
    #pragma unroll
    for (int m = 0; m < MI; ++m) af[m] = *(const bf8_t*)&sA[(wr + m * 16 + fr) * 32 + kg];
    #pragma unroll
    for (int n = 0; n < 4; ++n) bfv[n] = *(const bf8_t*)&sB[(wc + n * 16 + fr) * 32 + kg];
    #pragma unroll
    for (int m = 0; m < MI; ++m)
      #pragma unroll
      for (int n = 0; n < 4; ++n) acc[m][n] = MFMA16(af[m], bfv[n], acc[m][n]);
    __syncthreads();
  }

  const int r0 = (lane >> 4) * 4;
  #pragma unroll
  for (int m = 0; m < MI; ++m) {
    #pragma unroll
    for (int n = 0; n < 4; ++n) {
      const long col = colBase + wc + n * 16 + fr;
      const float bv = bias[col];
      #pragma unroll
      for (int j = 0; j < 4; ++j) {
        const long row = rowBase + wr + m * 16 + r0 + j;
        float v = acc[m][n][j] + bv;
        if (EPI == EPI_F32) {
          outF[row * N + col] = v;
        } else if (EPI == EPI_GATE) {
          const int b = (int)(row >> 10);  // S = 1024
          const float g = gate[(long)b * 6144 + col];
          outF[row * N + col] = v * g + res[row * N + col];
        } else {  // tanh-GELU -> bf16
          const float t = 0.7978845608028654f * (v + 0.044715f * v * v * v);
          const float e = __expf(2.0f * t);
          const float th = 1.0f - 2.0f / (e + 1.0f);
          outB[row * N + col] = f2bf(0.5f * v * (1.0f + th));
        }
      }
    }
  }
}

// ---------------------------------------------------------------- LayerNorm + adaLN modulation -> bf16
__global__ __launch_bounds__(256)
void ln_mod(const float* __restrict__ h, const float* __restrict__ gamma, const float* __restrict__ beta,
            const float* shp, const float* scp, int bstride, u16* __restrict__ xb) {
  __shared__ float red[8];
  const int row = blockIdx.x;
  const int b = row >> 10;
  const int t = threadIdx.x;
  const float* hp = h + (long)row * 1024;
  float4 x = *(const float4*)&hp[t * 4];
  float s = x.x + x.y + x.z + x.w;
  #pragma unroll
  for (int o = 32; o > 0; o >>= 1) s += __shfl_down(s, o);
  const int lane = t & 63, wid = t >> 6;
  if (lane == 0) red[wid] = s;
  __syncthreads();
  const float mean = (red[0] + red[1] + red[2] + red[3]) * 0.0009765625f;
  const float d0 = x.x - mean, d1 = x.y - mean, d2 = x.z - mean, d3 = x.w - mean;
  float vs = d0 * d0 + d1 * d1 + d2 * d2 + d3 * d3;
  #pragma unroll
  for (int o = 32; o > 0; o >>= 1) vs += __shfl_down(vs, o);
  if (lane == 0) red[4 + wid] = vs;
  __syncthreads();
  const float var = (red[4] + red[5] + red[6] + red[7]) * 0.0009765625f;
  const float inv = rsqrtf(var + 1e-5f);
  const int d = t * 4;
  const float4 gg = *(const float4*)&gamma[d];
  const float4 bb = *(const float4*)&beta[d];
  const float4 sh = *(const float4*)&shp[(long)b * bstride + d];
  const float4 sc = *(const float4*)&scp[(long)b * bstride + d];
  union { u16 u[4]; uint2 v; } pk;
  pk.u[0] = f2bf((d0 * inv * gg.x + bb.x) * (1.0f + sc.x) + sh.x);
  pk.u[1] = f2bf((d1 * inv * gg.y + bb.y) * (1.0f + sc.y) + sh.y);
  pk.u[2] = f2bf((d2 * inv * gg.z + bb.z) * (1.0f + sc.z) + sh.z);
  pk.u[3] = f2bf((d3 * inv * gg.w + bb.w) * (1.0f + sc.w) + sh.w);
  *(uint2*)&xb[(long)row * 1024 + d] = pk.v;
}

// ---------------------------------------------------------------- RoPE split q/k -> bf16 [B][H][S][64]
__global__ __launch_bounds__(256)
void rope_split(const float* __restrict__ qkv, const float* __restrict__ ct, const float* __restrict__ st,
                u16* __restrict__ qb, u16* __restrict__ kb) {
  const int row = blockIdx.x;  // b*1024 + s
  const int b = row >> 10, s = row & 1023;
  const float* rp = qkv + (long)row * 3072;
  const int t = threadIdx.x;
  #pragma unroll
  for (int which = 0; which < 2; ++which) {
    const float* xp = rp + which * 1024;
    u16* op = which ? kb : qb;
    #pragma unroll
    for (int j = 0; j < 2; ++j) {
      const int p = t + j * 256;          // pair index 0..511
      const int h = p >> 5, i = p & 31;
      const float xe = xp[h * 64 + 2 * i], xo = xp[h * 64 + 2 * i + 1];
      const float c = ct[s * 32 + i], sn = st[s * 32 + i];
      const long base = (((long)(b * 16 + h)) * 1024 + s) * 64 + 2 * i;
      op[base] = f2bf(xe * c - xo * sn);
      op[base + 1] = f2bf(xe * sn + xo * c);
    }
  }
}

// ---------------------------------------------------------------- V transpose: qkv v-part -> vt [bh][64][1024] bf16
__global__ __launch_bounds__(256)
void v_transpose(const float* __restrict__ qkv, u16* __restrict__ vt) {
  __shared__ u16 tile[32][34];
  const int s0 = blockIdx.x * 32;
  const int h = blockIdx.y;
  const int bz = blockIdx.z, b = bz >> 1, dt = bz & 1;
  const int tx = threadIdx.x & 31, ty = threadIdx.x >> 5;
  #pragma unroll
  for (int i = 0; i < 32; i += 8)
    tile[ty + i][tx] = f2bf(qkv[(long)(b * 1024 + s0 + ty + i) * 3072 + 2048 + h * 64 + dt * 32 + tx]);
  __syncthreads();
  #pragma unroll
  for (int i = 0; i < 32; i += 8)
    vt[((long)(b * 16 + h) * 64 + dt * 32 + ty + i) * 1024 + s0 + tx] = tile[tx][ty + i];
}

// ---------------------------------------------------------------- flash attention
// Block: (q-tile of 64, h, b); 4 waves, wave w owns q-rows [q0+16w, q0+16w+16).
// S^T = mfma(K, Q): lane holds q = lane&15, k = kt*16 + (lane>>4)*4 + j  -> online softmax lane-uniform in q.
// PV: O^T = mfma(V^T, P^T): P round-trips through 1KB/wave LDS to reshape into A-style frag.
DEV void attn_body(bf8_t (&kcur)[4][2], bf8_t (&knxt)[4][2], const bf8_t (&qf)[2],
                   f4_t (&oacc)[4], float& m, float& psum, int kc,
                   const u16* __restrict__ Kp, const u16* __restrict__ Vt,
                   const float* smadd, u16* myP, int fr, int g) {
  const f4_t zero = {0.0f, 0.0f, 0.0f, 0.0f};
  bf8_t vf[4][2];
  #pragma unroll
  for (int dt = 0; dt < 4; ++dt)
    #pragma unroll
    for (int ks = 0; ks < 2; ++ks)
      vf[dt][ks] = *(const bf8_t*)&Vt[(long)(dt * 16 + fr) * 1024 + kc + ks * 32 + g * 8];
  f4_t st[4];
  #pragma unroll
  for (int kt = 0; kt < 4; ++kt) {
    st[kt] = MFMA16(kcur[kt][0], qf[0], zero);
    st[kt] = MFMA16(kcur[kt][1], qf[1], st[kt]);
  }
  {  // prefetch next chunk's K
    const int kn = (kc + 64) & 1023;
    #pragma unroll
    for (int kt = 0; kt < 4; ++kt)
      #pragma unroll
      for (int dh = 0; dh < 2; ++dh)
        knxt[kt][dh] = *(const bf8_t*)&Kp[(long)(kn + kt * 16 + fr) * 64 + dh * 32 + g * 8];
  }
  float p[4][4];
  float cm = -3.402823466e38f;
  #pragma unroll
  for (int kt = 0; kt < 4; ++kt)
    #pragma unroll
    for (int j = 0; j < 4; ++j) {
      p[kt][j] = st[kt][j] * 0.125f + smadd[kc + kt * 16 + g * 4 + j];
      cm = fmaxf(cm, p[kt][j]);
    }
  cm = fmaxf(cm, __shfl_xor(cm, 16));
  cm = fmaxf(cm, __shfl_xor(cm, 32));
  const float nm = fmaxf(m, cm);
  const float sc = __expf(m - nm);
  m = nm;
  float ls = 0.0f;
  #pragma unroll
  for (int kt = 0; kt < 4; ++kt)
    #pragma unroll
    for (int j = 0; j < 4; ++j) {
      p[kt][j] = __expf(p[kt][j] - nm);
      ls += p[kt][j];
    }
  psum = psum * sc + ls;
  #pragma unroll
  for (int dt = 0; dt < 4; ++dt)
    #pragma unroll
    for (int j = 0; j < 4; ++j) oacc[dt][j] *= sc;
  // P -> LDS (block-major: k-block kb of 8, addr = (kb*16 + q)*8 u16)
  #pragma unroll
  for (int kt = 0; kt < 4; ++kt) {
    const int kb = kt * 2 + (g >> 1);
    uint2 w;
    w.x = (uint32_t)f2bf(p[kt][0]) | ((uint32_t)f2bf(p[kt][1]) << 16);
    w.y = (uint32_t)f2bf(p[kt][2]) | ((uint32_t)f2bf(p[kt][3]) << 16);
    *(uint2*)&myP[(kb * 16 + fr) * 8 + (g & 1) * 4] = w;
  }
  bf8_t pa0 = *(const bf8_t*)&myP[(g * 16 + fr) * 8];
  bf8_t pa1 = *(const bf8_t*)&myP[((4 + g) * 16 + fr) * 8];
  #pragma unroll
  for (int dt = 0; dt < 4; ++dt) {
    oacc[dt] = MFMA16(vf[dt][0], pa0, oacc[dt]);
    oacc[dt] = MFMA16(vf[dt][1], pa1, oacc[dt]);
  }
}

__global__ __launch_bounds__(256)
void attn_k(const u16* __restrict__ qb, const u16* __restrict__ kb, const u16* __restrict__ vt,
            const float* __restrict__ amask, u16* __restrict__ ob) {
  __shared__ float smadd[1024];
  __shared__ u16 pl[4][1024];
  const int q0 = blockIdx.x * 64;
  const int h = blockIdx.y, b = blockIdx.z;
  const long bh = b * 16 + h;
  const int tid = threadIdx.x, lane = tid & 63, wid = tid >> 6;
  const int fr = lane & 15, g = lane >> 4;

  for (int i = tid; i < 1024; i += 256)
    smadd[i] = (1.0f - amask[b * 1024 + i]) * -3.402823466e38f;
  __syncthreads();

  const u16* Q = qb + (bh * 1024 + q0 + wid * 16) * 64;
  const u16* Kp = kb + bh * 1024 * 64;
  const u16* Vt = vt + bh * 64 * 1024;
  u16* myP = &pl[wid][0];

  bf8_t qf[2];
  qf[0] = *(const bf8_t*)&Q[fr * 64 + g * 8];
  qf[1] = *(const bf8_t*)&Q[fr * 64 + 32 + g * 8];

  const f4_t zero = {0.0f, 0.0f, 0.0f, 0.0f};
  f4_t oacc[4];
  #pragma unroll
  for (int dt = 0; dt < 4; ++dt) oacc[dt] = zero;
  float m = -1e30f, psum = 0.0f;

  bf8_t kfA[4][2], kfB[4][2];
  #pragma unroll
  for (int kt = 0; kt < 4; ++kt)
    #pragma unroll
    for (int dh = 0; dh < 2; ++dh)
      kfA[kt][dh] = *(const bf8_t*)&Kp[(long)(kt * 16 + fr) * 64 + dh * 32 + g * 8];

  for (int kc = 0; kc < 1024; kc += 128) {
    attn_body(kfA, kfB, qf, oacc, m, psum, kc, Kp, Vt, smadd, myP, fr, g);
    attn_body(kfB, kfA, qf, oacc, m, psum, kc + 64, Kp, Vt, smadd, myP, fr, g);
  }

  float ts = psum + __shfl_xor(psum, 16);
  ts += __shfl_xor(ts, 32);
  const float inv = 1.0f / ts;
  const long qrow = (long)b * 1024 + q0 + wid * 16 + fr;
  #pragma unroll
  for (int dt = 0; dt < 4; ++dt) {
    union { u16 u[4]; uint2 v; } pk;
    #pragma unroll
    for (int j = 0; j < 4; ++j) pk.u[j] = f2bf(oacc[dt][j] * inv);
    *(uint2*)&ob[qrow * 1024 + h * 64 + dt * 16 + g * 4] = pk.v;
  }
}

// ---------------------------------------------------------------- small kernels
__global__ void rope_tables(float* ct, float* st) {
  const int i = blockIdx.x * 256 + threadIdx.x;  // S*32 = 32768
  const int s = i >> 5, k = i & 31;
  const float freq = __expf(-9.210340371976184f * (float)(2 * k) / 64.0f);
  const float a = (float)s * freq;
  ct[i] = cosf(a);
  st[i] = sinf(a);
}

__global__ void init_hs(const float* __restrict__ e, const float* __restrict__ wpe, float* __restrict__ hs) {
  const long i = (long)blockIdx.x * 256 + threadIdx.x;
  float4 a = ((const float4*)e)[i];
  const float4 w = ((const float4*)wpe)[i & 262143];
  a.x += w.x; a.y += w.y; a.z += w.z; a.w += w.w;
  ((float4*)hs)[i] = a;
}

__global__ void time_proj_k(const float* __restrict__ ts, float* __restrict__ tproj) {
  const int j = blockIdx.x * 256 + threadIdx.x;  // 0..511
  const int b = blockIdx.y;
  const float tf = __expf(-9.210340371976184f * (float)(j & 255) / 256.0f);
  const float a = ts[b] * tf * 1000.0f;
  tproj[b * 512 + j] = (j < 256) ? cosf(a) : sinf(a);
}

__global__ void time_mlp1(const float* __restrict__ tproj, const float* __restrict__ w1,
                          const float* __restrict__ b1, float* __restrict__ h1) {
  const int d = blockIdx.x * 256 + threadIdx.x;
  const int b = blockIdx.y;
  float acc = b1[d];
  for (int j = 0; j < 512; ++j) acc += tproj[b * 512 + j] * w1[(long)j * 1024 + d];
  h1[b * 1024 + d] = acc / (1.0f + __expf(-acc));
}

__global__ void time_mlp2(const float* __restrict__ h1, const float* __restrict__ w2,
                          const float* __restrict__ b2, float* __restrict__ emb) {
  const int d = blockIdx.x * 256 + threadIdx.x;
  const int b = blockIdx.y;
  float acc = b2[d];
  for (int j = 0; j < 1024; ++j) acc += h1[b * 1024 + j] * w2[(long)j * 1024 + d];
  emb[b * 1024 + d] = acc;
}

__global__ void silu_k(const float* __restrict__ in, float* __restrict__ out, int n) {
  const int i = blockIdx.x * 256 + threadIdx.x;
  if (i < n) { const float v = in[i]; out[i] = v / (1.0f + __expf(-v)); }
}

__global__ void adaln_k(const float* __restrict__ se, const float* __restrict__ aw,
                        const float* __restrict__ ab, float* __restrict__ adaln) {
  const int j = blockIdx.x * 256 + threadIdx.x;  // 0..6143
  const int b = blockIdx.y;
  float acc = ab[j];
  for (int k = 0; k < 1024; ++k) acc += se[b * 1024 + k] * aw[(long)k * 6144 + j];
  adaln[b * 6144 + j] = acc;
}

__global__ void build_mods(const float* __restrict__ sst, const float* __restrict__ adaln,
                           const float* __restrict__ fsst, const float* __restrict__ emb,
                           float* __restrict__ modAll, float* __restrict__ fmod) {
  const int i = blockIdx.x * 256 + threadIdx.x;
  if (i < 98304) {
    const int d = i & 1023;
    const int rest = i >> 10;
    const int slot = rest % 6;
    const int t2 = rest / 6;
    const int bb = t2 & 1, l = t2 >> 1;
    modAll[i] = sst[(long)(l * 6 + slot) * 1024 + d] + adaln[bb * 6144 + slot * 1024 + d];
  } else if (i < 98304 + 4096) {
    const int j = i - 98304;
    const int d = j & 1023;
    const int slot = (j >> 10) & 1;
    const int bb = j >> 11;
    fmod[j] = fsst[slot * 1024 + d] + emb[bb * 1024 + d];
  }
}

// ---------------------------------------------------------------- launch
extern "C" void kernel_launch(void* const* d_in, const int* in_sizes, int n_in,
                              void* d_out, int out_size, void* d_ws, size_t ws_size,
                              hipStream_t stream) {
  const float* inp_emb = (const float*)d_in[0];
  const float* amask  = (const float*)d_in[1];
  const float* tstep  = (const float*)d_in[2];
  const float* wpe    = (const float*)d_in[3];
  const float* ln1_g  = (const float*)d_in[4];
  const float* ln1_b  = (const float*)d_in[5];
  const float* attn_w = (const float*)d_in[6];
  const float* attn_b = (const float*)d_in[7];
  const float* projw  = (const float*)d_in[8];
  const float* projb  = (const float*)d_in[9];
  const float* ln2_g  = (const float*)d_in[10];
  const float* ln2_b  = (const float*)d_in[11];
  const float* fcw    = (const float*)d_in[12];
  const float* fcb    = (const float*)d_in[13];
  const float* pw2    = (const float*)d_in[14];
  const float* pb2    = (const float*)d_in[15];
  const float* sst    = (const float*)d_in[16];
  const float* te_w1  = (const float*)d_in[17];
  const float* te_b1  = (const float*)d_in[18];
  const float* te_w2  = (const float*)d_in[19];
  const float* te_b2  = (const float*)d_in[20];
  const float* ada_w  = (const float*)d_in[21];
  const float* ada_b  = (const float*)d_in[22];
  const float* lnf_g  = (const float*)d_in[23];
  const float* lnf_b  = (const float*)d_in[24];
  const float* fsst   = (const float*)d_in[25];
  const float* out_w  = (const float*)d_in[26];
  const float* out_b  = (const float*)d_in[27];
  float* out = (float*)d_out;
  (void)in_sizes; (void)n_in; (void)out_size; (void)ws_size;

  char* wsb = (char*)d_ws;
  size_t off = 0;
  auto alloc = [&](size_t bytes) -> void* {
    void* p = wsb + off;
    off += (bytes + 255) & ~(size_t)255;
    return p;
  };
  u16* wtA = (u16*)alloc(3072ll * 1024 * 2);
  u16* wtP = (u16*)alloc(1024ll * 1024 * 2);
  u16* wtF = (u16*)alloc(4096ll * 1024 * 2);
  u16* wtQ = (u16*)alloc(1024ll * 4096 * 2);
  u16* wtO = (u16*)alloc(1024ll * 1024 * 2);
  float* hs   = (float*)alloc(2048ll * 1024 * 4);
  float* qkv  = (float*)alloc(2048ll * 3072 * 4);
  u16*   ffb  = (u16*)qkv;                     // alias: FF activations reuse qkv space
  u16* xb = (u16*)alloc(2048ll * 1024 * 2);
  u16* qb = (u16*)alloc(2048ll * 1024 * 2);
  u16* kb = (u16*)alloc(2048ll * 1024 * 2);
  u16* vt = (u16*)alloc(2048ll * 1024 * 2);
  u16* ob = (u16*)alloc(2048ll * 1024 * 2);
  float* ct    = (float*)alloc(32768 * 4);
  float* st    = (float*)alloc(32768 * 4);
  float* tproj = (float*)alloc(2 * 512 * 4);
  float* h1    = (float*)alloc(2 * 1024 * 4);
  float* emb   = (float*)alloc(2 * 1024 * 4);
  float* se    = (float*)alloc(2 * 1024 * 4);
  float* adaln = (float*)alloc(2 * 6144 * 4);
  float* modAll = (float*)alloc(8ll * 2 * 6 * 1024 * 4);
  float* fmod   = (float*)alloc(2 * 2 * 1024 * 4);

  rope_tables<<<128, 256, 0, stream>>>(ct, st);
  init_hs<<<2048, 256, 0, stream>>>(inp_emb, wpe, hs);
  time_proj_k<<<dim3(2, 2), 256, 0, stream>>>(tstep, tproj);
  time_mlp1<<<dim3(4, 2), 256, 0, stream>>>(tproj, te_w1, te_b1, h1);
  time_mlp2<<<dim3(4, 2), 256, 0, stream>>>(h1, te_w2, te_b2, emb);
  silu_k<<<8, 256, 0, stream>>>(emb, se, 2048);
  adaln_k<<<dim3(24, 2), 256, 0, stream>>>(se, ada_w, ada_b, adaln);
  build_mods<<<400, 256, 0, stream>>>(sst, adaln, fsst, emb, modAll, fmod);
  transpose_k<<<dim3(32, 32), 256, 0, stream>>>(out_w, wtO, 1024, 1024);

  for (int l = 0; l < 8; ++l) {
    const float* ml = modAll + (long)l * 12288;
    transpose_k<<<dim3(96, 32), 256, 0, stream>>>(attn_w + (long)l * 1024 * 3072, wtA, 1024, 3072);
    transpose_k<<<dim3(32, 32), 256, 0, stream>>>(projw + (long)l * 1024 * 1024, wtP, 1024, 1024);
    transpose_k<<<dim3(128, 32), 256, 0, stream>>>(fcw + (long)l * 1024 * 4096, wtF, 1024, 4096);
    transpose_k<<<dim3(32, 128), 256, 0, stream>>>(pw2 + (long)l * 4096 * 1024, wtQ, 4096, 1024);

    ln_mod<<<2048, 256, 0, stream>>>(hs, ln1_g + l * 1024, ln1_b + l * 1024,
                                     ml + 0 * 1024, ml + 1 * 1024, 6144, xb);
    gemm_bt<128, EPI_F32><<<dim3(16, 24), 256, 0, stream>>>(xb, wtA, attn_b + l * 3072,
                                                            qkv, nullptr, nullptr, nullptr, 2048, 3072, 1024);
    rope_split<<<2048, 256, 0, stream>>>(qkv, ct, st, qb, kb);
    v_transpose<<<dim3(32, 16, 4), 256, 0, stream>>>(qkv, vt);
    attn_k<<<dim3(16, 16, 2), 256, 0, stream>>>(qb, kb, vt, amask, ob);
    gemm_bt<64, EPI_GATE><<<dim3(32, 8), 256, 0, stream>>>(ob, wtP, projb + l * 1024,
                                                           hs, nullptr, ml + 2 * 1024, hs, 2048, 1024, 1024);
    ln_mod<<<2048, 256, 0, stream>>>(hs, ln2_g + l * 1024, ln2_b + l * 1024,
                                     ml + 3 * 1024, ml + 4 * 1024, 6144, xb);
    gemm_bt<128, EPI_GELU><<<dim3(16, 32), 256, 0, stream>>>(xb, wtF, fcb + l * 4096,
                                                             nullptr, ffb, nullptr, nullptr, 2048, 4096, 1024);
    gemm_bt<64, EPI_GATE><<<dim3(32, 8), 256, 0, stream>>>(ffb, wtQ, pb2 + l * 1024,
                                                           hs, nullptr, ml + 5 * 1024, hs, 2048, 1024, 4096);
  }

  ln_mod<<<2048, 256, 0, stream>>>(hs, lnf_g, lnf_b, fmod + 0, fmod + 1024, 2048, xb);
  gemm_bt<64, EPI_F32><<<dim3(32, 8), 256, 0, stream>>>(xb, wtO, out_b,
                                                        out, nullptr, nullptr, nullptr, 2048, 1024, 1024);
}

// Round 3
// 1951.432 us; speedup vs baseline: 1.5083x; 1.1574x over previous
//
#include <hip/hip_runtime.h>
#include <stdint.h>

typedef unsigned short u16;
typedef __attribute__((ext_vector_type(8))) short bf8_t;   // 8 x bf16
typedef __attribute__((ext_vector_type(4))) float f4_t;

#define DEV static __device__ __forceinline__
#define MFMA16(a, b, c) __builtin_amdgcn_mfma_f32_16x16x32_bf16((a), (b), (c), 0, 0, 0)
#define GLDS(gp, lp) __builtin_amdgcn_global_load_lds((const __attribute__((address_space(1))) void*)(gp), \
                                                      (__attribute__((address_space(3))) void*)(lp), 16, 0, 0)

DEV u16 f2bf(float f) {  // RNE float->bf16
  union { float f; uint32_t u; } x; x.f = f;
  uint32_t r = x.u + 0x7FFFu + ((x.u >> 16) & 1u);
  return (u16)(r >> 16);
}

// ---------------------------------------------------------------- transpose body (64x64, vectorized)
DEV void transpose_body(const float* __restrict__ W, u16* __restrict__ WT, int K, int N,
                        int n0, int k0, u16 (*tl)[66]) {
  const int t = threadIdx.x;
  const int tx = t & 15, ty = t >> 4;
  #pragma unroll
  for (int i = 0; i < 64; i += 16) {
    const float4 v = *(const float4*)&W[(long)(k0 + ty + i) * N + n0 + tx * 4];
    tl[tx * 4 + 0][ty + i] = f2bf(v.x);
    tl[tx * 4 + 1][ty + i] = f2bf(v.y);
    tl[tx * 4 + 2][ty + i] = f2bf(v.z);
    tl[tx * 4 + 3][ty + i] = f2bf(v.w);
  }
  __syncthreads();
  const int c = t & 15, r = t >> 4;
  #pragma unroll
  for (int i = 0; i < 64; i += 16) {
    const u16* p = &tl[r + i][c * 4];
    uint2 w;
    w.x = (uint32_t)p[0] | ((uint32_t)p[1] << 16);
    w.y = (uint32_t)p[2] | ((uint32_t)p[3] << 16);
    *(uint2*)&WT[(long)(n0 + r + i) * K + k0 + c * 4] = w;
  }
}

// generic single transpose: grid (N/64, K/64)
__global__ __launch_bounds__(256) void transpose_k(const float* __restrict__ W, u16* __restrict__ WT,
                                                   int K, int N) {
  __shared__ u16 tl[64][66];
  transpose_body(W, WT, K, N, blockIdx.x * 64, blockIdx.y * 64, tl);
}

// all 4 per-layer weight transposes in one launch (3072 blocks)
__global__ __launch_bounds__(256)
void transpose4_k(const float* __restrict__ w0, u16* __restrict__ o0,   // attn_w  1024x3072
                  const float* __restrict__ w1, u16* __restrict__ o1,   // projw   1024x1024
                  const float* __restrict__ w2, u16* __restrict__ o2,   // fcw     1024x4096
                  const float* __restrict__ w3, u16* __restrict__ o3) { // pw2     4096x1024
  __shared__ u16 tl[64][66];
  int bid = blockIdx.x;
  const float* W; u16* O; int K, N, nbx;
  if (bid < 768)        {             W = w0; O = o0; K = 1024; N = 3072; nbx = 48; }
  else if (bid < 1024)  { bid -= 768; W = w1; O = o1; K = 1024; N = 1024; nbx = 16; }
  else if (bid < 2048)  { bid -= 1024; W = w2; O = o2; K = 1024; N = 4096; nbx = 64; }
  else                  { bid -= 2048; W = w3; O = o3; K = 4096; N = 1024; nbx = 16; }
  transpose_body(W, O, K, N, (bid % nbx) * 64, (bid / nbx) * 64, tl);
}

// ---------------------------------------------------------------- GEMM (m97 structure, tile/splitK-templated)
enum { EPI_F32 = 0, EPI_GATE = 1, EPI_GELU = 2, EPI_RAW = 3 };

template <int BM, int EPI, int KS>
__global__ __launch_bounds__(256)
void gemm_bt(const u16* __restrict__ A, const u16* __restrict__ BT, const float* __restrict__ bias,
             float* outF, u16* outB, const float* gate, const float* res, int M, int N, int K) {
  constexpr int MI = BM / 32;
  __shared__ u16 sA[BM * 32];
  __shared__ u16 sB[128 * 32];
  const int tid = threadIdx.x, lane = tid & 63, wid = tid >> 6;
  const long rowBase = (long)blockIdx.x * BM;
  const long colBase = (long)blockIdx.y * 128;
  const int kz = (KS > 1) ? blockIdx.z : 0;
  const int kbeg = kz * (K / KS), kend = kbeg + K / KS;
  const int wr = (wid >> 1) * (BM / 2), wc = (wid & 1) * 64;
  const int fr = lane & 15, kg = (lane >> 4) * 8;

  const f4_t zero = {0.0f, 0.0f, 0.0f, 0.0f};
  f4_t acc[MI][4];
  #pragma unroll
  for (int i = 0; i < MI; ++i)
    #pragma unroll
    for (int j = 0; j < 4; ++j) acc[i][j] = zero;

  const int sr = lane >> 2, scol = (lane & 3) * 8;
  const int c0 = wid * 2;
  const u16 *Ag0, *Ag1 = nullptr, *Bg0, *Bg1;
  u16 *lA0, *lA1 = nullptr, *lB0, *lB1;
  if constexpr (BM == 128) {
    Ag0 = A + (rowBase + c0 * 16 + sr) * (long)K + scol;
    Ag1 = A + (rowBase + c0 * 16 + 16 + sr) * (long)K + scol;
    lA0 = &sA[(c0 * 16) * 32];
    lA1 = &sA[(c0 * 16 + 16) * 32];
  } else {  // BM == 64
    Ag0 = A + (rowBase + wid * 16 + sr) * (long)K + scol;
    lA0 = &sA[(wid * 16) * 32];
  }
  Bg0 = BT + (colBase + c0 * 16 + sr) * (long)K + scol;
  Bg1 = BT + (colBase + c0 * 16 + 16 + sr) * (long)K + scol;
  lB0 = &sB[(c0 * 16) * 32];
  lB1 = &sB[(c0 * 16 + 16) * 32];

  for (int k0 = kbeg; k0 < kend; k0 += 32) {
    GLDS(Ag0 + k0, lA0);
    if constexpr (BM == 128) GLDS(Ag1 + k0, lA1);
    GLDS(Bg0 + k0, lB0);
    GLDS(Bg1 + k0, lB1);
    __syncthreads();
    bf8_t af[MI], bfv[4];
    #pragma unroll
    for (int m = 0; m < MI; ++m) af[m] = *(const bf8_t*)&sA[(wr + m * 16 + fr) * 32 + kg];
    #pragma unroll
    for (int n = 0; n < 4; ++n) bfv[n] = *(const bf8_t*)&sB[(wc + n * 16 + fr) * 32 + kg];
    #pragma unroll
    for (int m = 0; m < MI; ++m)
      #pragma unroll
      for (int n = 0; n < 4; ++n) acc[m][n] = MFMA16(af[m], bfv[n], acc[m][n]);
    __syncthreads();
  }

  const int r0 = (lane >> 4) * 4;
  #pragma unroll
  for (int m = 0; m < MI; ++m) {
    #pragma unroll
    for (int n = 0; n < 4; ++n) {
      const long col = colBase + wc + n * 16 + fr;
      const float bv = (EPI == EPI_RAW) ? 0.0f : bias[col];
      #pragma unroll
      for (int j = 0; j < 4; ++j) {
        const long row = rowBase + wr + m * 16 + r0 + j;
        float v = acc[m][n][j] + bv;
        if (EPI == EPI_F32) {
          outF[row * N + col] = v;
        } else if (EPI == EPI_RAW) {
          outF[((long)kz * M + row) * N + col] = v;
        } else if (EPI == EPI_GATE) {
          const int b = (int)(row >> 10);  // S = 1024
          const float g = gate[(long)b * 6144 + col];
          outF[row * N + col] = v * g + res[row * N + col];
        } else {  // tanh-GELU -> bf16
          const float t = 0.7978845608028654f * (v + 0.044715f * v * v * v);
          const float e = __expf(2.0f * t);
          const float th = 1.0f - 2.0f / (e + 1.0f);
          outB[row * N + col] = f2bf(0.5f * v * (1.0f + th));
        }
      }
    }
  }
}

// split-K reduce + bias + gate + residual (N == 1024, M == 2048)
__global__ __launch_bounds__(256)
void reduce_gate(const float* __restrict__ part, const float* __restrict__ bias,
                 const float* __restrict__ gate, float* __restrict__ hs) {
  const long i = (long)blockIdx.x * 256 + threadIdx.x;  // over 2048*1024/4
  const long e0 = i * 4;
  const int col = (int)(e0 & 1023);
  const int row = (int)(e0 >> 10);
  const int b = row >> 10;
  const f4_t p = *(const f4_t*)&part[e0];
  const f4_t q = *(const f4_t*)&part[e0 + 2048ll * 1024];
  const f4_t bv = *(const f4_t*)&bias[col];
  const f4_t gv = *(const f4_t*)&gate[(long)b * 6144 + col];
  const f4_t r = *(const f4_t*)&hs[e0];
  f4_t o;
  #pragma unroll
  for (int j = 0; j < 4; ++j) o[j] = (p[j] + q[j] + bv[j]) * gv[j] + r[j];
  *(f4_t*)&hs[e0] = o;
}

// ---------------------------------------------------------------- LayerNorm + adaLN modulation -> bf16
__global__ __launch_bounds__(256)
void ln_mod(const float* __restrict__ h, const float* __restrict__ gamma, const float* __restrict__ beta,
            const float* shp, const float* scp, int bstride, u16* __restrict__ xb) {
  __shared__ float red[8];
  const int row = blockIdx.x;
  const int b = row >> 10;
  const int t = threadIdx.x;
  const float* hp = h + (long)row * 1024;
  float4 x = *(const float4*)&hp[t * 4];
  float s = x.x + x.y + x.z + x.w;
  #pragma unroll
  for (int o = 32; o > 0; o >>= 1) s += __shfl_down(s, o);
  const int lane = t & 63, wid = t >> 6;
  if (lane == 0) red[wid] = s;
  __syncthreads();
  const float mean = (red[0] + red[1] + red[2] + red[3]) * 0.0009765625f;
  const float d0 = x.x - mean, d1 = x.y - mean, d2 = x.z - mean, d3 = x.w - mean;
  float vs = d0 * d0 + d1 * d1 + d2 * d2 + d3 * d3;
  #pragma unroll
  for (int o = 32; o > 0; o >>= 1) vs += __shfl_down(vs, o);
  if (lane == 0) red[4 + wid] = vs;
  __syncthreads();
  const float var = (red[4] + red[5] + red[6] + red[7]) * 0.0009765625f;
  const float inv = rsqrtf(var + 1e-5f);
  const int d = t * 4;
  const float4 gg = *(const float4*)&gamma[d];
  const float4 bb = *(const float4*)&beta[d];
  const float4 sh = *(const float4*)&shp[(long)b * bstride + d];
  const float4 sc = *(const float4*)&scp[(long)b * bstride + d];
  union { u16 u[4]; uint2 v; } pk;
  pk.u[0] = f2bf((d0 * inv * gg.x + bb.x) * (1.0f + sc.x) + sh.x);
  pk.u[1] = f2bf((d1 * inv * gg.y + bb.y) * (1.0f + sc.y) + sh.y);
  pk.u[2] = f2bf((d2 * inv * gg.z + bb.z) * (1.0f + sc.z) + sh.z);
  pk.u[3] = f2bf((d3 * inv * gg.w + bb.w) * (1.0f + sc.w) + sh.w);
  *(uint2*)&xb[(long)row * 1024 + d] = pk.v;
}

// ---------------------------------------------------------------- RoPE split q/k -> bf16 [B][H][S][64]
__global__ __launch_bounds__(256)
void rope_split(const float* __restrict__ qkv, const float* __restrict__ ct, const float* __restrict__ st,
                u16* __restrict__ qb, u16* __restrict__ kb) {
  const int row = blockIdx.x;  // b*1024 + s
  const int b = row >> 10, s = row & 1023;
  const float* rp = qkv + (long)row * 3072;
  const int t = threadIdx.x;
  #pragma unroll
  for (int which = 0; which < 2; ++which) {
    const float* xp = rp + which * 1024;
    u16* op = which ? kb : qb;
    #pragma unroll
    for (int j = 0; j < 2; ++j) {
      const int p = t + j * 256;          // pair index 0..511
      const int h = p >> 5, i = p & 31;
      const float xe = xp[h * 64 + 2 * i], xo = xp[h * 64 + 2 * i + 1];
      const float c = ct[s * 32 + i], sn = st[s * 32 + i];
      const long base = (((long)(b * 16 + h)) * 1024 + s) * 64 + 2 * i;
      op[base] = f2bf(xe * c - xo * sn);
      op[base + 1] = f2bf(xe * sn + xo * c);
    }
  }
}

// ---------------------------------------------------------------- V transpose -> vt [bh][64][1024] bf16
__global__ __launch_bounds__(256)
void v_transpose(const float* __restrict__ qkv, u16* __restrict__ vt) {
  __shared__ u16 tl[64][66];
  const int s0 = blockIdx.x * 64;
  const int h = blockIdx.y, b = blockIdx.z;
  const int t = threadIdx.x;
  const int tx = t & 15, ty = t >> 4;
  #pragma unroll
  for (int i = 0; i < 64; i += 16) {
    const float4 v = *(const float4*)&qkv[(long)(b * 1024 + s0 + ty + i) * 3072 + 2048 + h * 64 + tx * 4];
    tl[tx * 4 + 0][ty + i] = f2bf(v.x);
    tl[tx * 4 + 1][ty + i] = f2bf(v.y);
    tl[tx * 4 + 2][ty + i] = f2bf(v.z);
    tl[tx * 4 + 3][ty + i] = f2bf(v.w);
  }
  __syncthreads();
  const int c = t & 15, r = t >> 4;
  #pragma unroll
  for (int i = 0; i < 64; i += 16) {
    const u16* p = &tl[r + i][c * 4];
    uint2 w;
    w.x = (uint32_t)p[0] | ((uint32_t)p[1] << 16);
    w.y = (uint32_t)p[2] | ((uint32_t)p[3] << 16);
    *(uint2*)&vt[((long)(b * 16 + h) * 64 + r + i) * 1024 + s0 + c * 4] = w;
  }
}

// ---------------------------------------------------------------- flash attention (unchanged from round 2)
DEV void attn_body(bf8_t (&kcur)[4][2], bf8_t (&knxt)[4][2], const bf8_t (&qf)[2],
                   f4_t (&oacc)[4], float& m, float& psum, int kc,
                   const u16* __restrict__ Kp, const u16* __restrict__ Vt,
                   const float* smadd, u16* myP, int fr, int g) {
  const f4_t zero = {0.0f, 0.0f, 0.0f, 0.0f};
  bf8_t vf[4][2];
  #pragma unroll
  for (int dt = 0; dt < 4; ++dt)
    #pragma unroll
    for (int ks = 0; ks < 2; ++ks)
      vf[dt][ks] = *(const bf8_t*)&Vt[(long)(dt * 16 + fr) * 1024 + kc + ks * 32 + g * 8];
  f4_t st[4];
  #pragma unroll
  for (int kt = 0; kt < 4; ++kt) {
    st[kt] = MFMA16(kcur[kt][0], qf[0], zero);
    st[kt] = MFMA16(kcur[kt][1], qf[1], st[kt]);
  }
  {  // prefetch next chunk's K
    const int kn = (kc + 64) & 1023;
    #pragma unroll
    for (int kt = 0; kt < 4; ++kt)
      #pragma unroll
      for (int dh = 0; dh < 2; ++dh)
        knxt[kt][dh] = *(const bf8_t*)&Kp[(long)(kn + kt * 16 + fr) * 64 + dh * 32 + g * 8];
  }
  float p[4][4];
  float cm = -3.402823466e38f;
  #pragma unroll
  for (int kt = 0; kt < 4; ++kt)
    #pragma unroll
    for (int j = 0; j < 4; ++j) {
      p[kt][j] = st[kt][j] * 0.125f + smadd[kc + kt * 16 + g * 4 + j];
      cm = fmaxf(cm, p[kt][j]);
    }
  cm = fmaxf(cm, __shfl_xor(cm, 16));
  cm = fmaxf(cm, __shfl_xor(cm, 32));
  const float nm = fmaxf(m, cm);
  const float sc = __expf(m - nm);
  m = nm;
  float ls = 0.0f;
  #pragma unroll
  for (int kt = 0; kt < 4; ++kt)
    #pragma unroll
    for (int j = 0; j < 4; ++j) {
      p[kt][j] = __expf(p[kt][j] - nm);
      ls += p[kt][j];
    }
  psum = psum * sc + ls;
  #pragma unroll
  for (int dt = 0; dt < 4; ++dt)
    #pragma unroll
    for (int j = 0; j < 4; ++j) oacc[dt][j] *= sc;
  #pragma unroll
  for (int kt = 0; kt < 4; ++kt) {
    const int kb = kt * 2 + (g >> 1);
    uint2 w;
    w.x = (uint32_t)f2bf(p[kt][0]) | ((uint32_t)f2bf(p[kt][1]) << 16);
    w.y = (uint32_t)f2bf(p[kt][2]) | ((uint32_t)f2bf(p[kt][3]) << 16);
    *(uint2*)&myP[(kb * 16 + fr) * 8 + (g & 1) * 4] = w;
  }
  bf8_t pa0 = *(const bf8_t*)&myP[(g * 16 + fr) * 8];
  bf8_t pa1 = *(const bf8_t*)&myP[((4 + g) * 16 + fr) * 8];
  #pragma unroll
  for (int dt = 0; dt < 4; ++dt) {
    oacc[dt] = MFMA16(vf[dt][0], pa0, oacc[dt]);
    oacc[dt] = MFMA16(vf[dt][1], pa1, oacc[dt]);
  }
}

__global__ __launch_bounds__(256)
void attn_k(const u16* __restrict__ qb, const u16* __restrict__ kb, const u16* __restrict__ vt,
            const float* __restrict__ amask, u16* __restrict__ ob) {
  __shared__ float smadd[1024];
  __shared__ u16 pl[4][1024];
  const int q0 = blockIdx.x * 64;
  const int h = blockIdx.y, b = blockIdx.z;
  const long bh = b * 16 + h;
  const int tid = threadIdx.x, lane = tid & 63, wid = tid >> 6;
  const int fr = lane & 15, g = lane >> 4;

  for (int i = tid; i < 1024; i += 256)
    smadd[i] = (1.0f - amask[b * 1024 + i]) * -3.402823466e38f;
  __syncthreads();

  const u16* Q = qb + (bh * 1024 + q0 + wid * 16) * 64;
  const u16* Kp = kb + bh * 1024 * 64;
  const u16* Vt = vt + bh * 64 * 1024;
  u16* myP = &pl[wid][0];

  bf8_t qf[2];
  qf[0] = *(const bf8_t*)&Q[fr * 64 + g * 8];
  qf[1] = *(const bf8_t*)&Q[fr * 64 + 32 + g * 8];

  const f4_t zero = {0.0f, 0.0f, 0.0f, 0.0f};
  f4_t oacc[4];
  #pragma unroll
  for (int dt = 0; dt < 4; ++dt) oacc[dt] = zero;
  float m = -1e30f, psum = 0.0f;

  bf8_t kfA[4][2], kfB[4][2];
  #pragma unroll
  for (int kt = 0; kt < 4; ++kt)
    #pragma unroll
    for (int dh = 0; dh < 2; ++dh)
      kfA[kt][dh] = *(const bf8_t*)&Kp[(long)(kt * 16 + fr) * 64 + dh * 32 + g * 8];

  for (int kc = 0; kc < 1024; kc += 128) {
    attn_body(kfA, kfB, qf, oacc, m, psum, kc, Kp, Vt, smadd, myP, fr, g);
    attn_body(kfB, kfA, qf, oacc, m, psum, kc + 64, Kp, Vt, smadd, myP, fr, g);
  }

  float ts = psum + __shfl_xor(psum, 16);
  ts += __shfl_xor(ts, 32);
  const float inv = 1.0f / ts;
  const long qrow = (long)b * 1024 + q0 + wid * 16 + fr;
  #pragma unroll
  for (int dt = 0; dt < 4; ++dt) {
    union { u16 u[4]; uint2 v; } pk;
    #pragma unroll
    for (int j = 0; j < 4; ++j) pk.u[j] = f2bf(oacc[dt][j] * inv);
    *(uint2*)&ob[qrow * 1024 + h * 64 + dt * 16 + g * 4] = pk.v;
  }
}

// ---------------------------------------------------------------- small kernels
__global__ void rope_tables(float* ct, float* st) {
  const int i = blockIdx.x * 256 + threadIdx.x;
  const int s = i >> 5, k = i & 31;
  const float freq = __expf(-9.210340371976184f * (float)(2 * k) / 64.0f);
  const float a = (float)s * freq;
  ct[i] = cosf(a);
  st[i] = sinf(a);
}

__global__ void init_hs(const float* __restrict__ e, const float* __restrict__ wpe, float* __restrict__ hs) {
  const long i = (long)blockIdx.x * 256 + threadIdx.x;
  float4 a = ((const float4*)e)[i];
  const float4 w = ((const float4*)wpe)[i & 262143];
  a.x += w.x; a.y += w.y; a.z += w.z; a.w += w.w;
  ((float4*)hs)[i] = a;
}

__global__ void time_proj_k(const float* __restrict__ ts, float* __restrict__ tproj) {
  const int j = blockIdx.x * 256 + threadIdx.x;  // 0..511
  const int b = blockIdx.y;
  const float tf = __expf(-9.210340371976184f * (float)(j & 255) / 256.0f);
  const float a = ts[b] * tf * 1000.0f;
  tproj[b * 512 + j] = (j < 256) ? cosf(a) : sinf(a);
}

__global__ __launch_bounds__(256)
void time_mlp1(const float* __restrict__ tproj, const float* __restrict__ w1,
               const float* __restrict__ b1, float* __restrict__ h1) {
  __shared__ float red[8][32];
  const int dl = threadIdx.x & 31, sl = threadIdx.x >> 5;
  const int d = blockIdx.x * 32 + dl, b = blockIdx.y;
  float acc = 0.0f;
  for (int j = sl * 64; j < sl * 64 + 64; ++j) acc += tproj[b * 512 + j] * w1[(long)j * 1024 + d];
  red[sl][dl] = acc;
  __syncthreads();
  if (threadIdx.x < 32) {
    const int dd = blockIdx.x * 32 + threadIdx.x;
    float a = b1[dd];
    #pragma unroll
    for (int s = 0; s < 8; ++s) a += red[s][threadIdx.x];
    h1[b * 1024 + dd] = a / (1.0f + __expf(-a));
  }
}

__global__ __launch_bounds__(256)
void time_mlp2(const float* __restrict__ h1, const float* __restrict__ w2,
               const float* __restrict__ b2, float* __restrict__ emb) {
  __shared__ float red[8][32];
  const int dl = threadIdx.x & 31, sl = threadIdx.x >> 5;
  const int d = blockIdx.x * 32 + dl, b = blockIdx.y;
  float acc = 0.0f;
  for (int j = sl * 128; j < sl * 128 + 128; ++j) acc += h1[b * 1024 + j] * w2[(long)j * 1024 + d];
  red[sl][dl] = acc;
  __syncthreads();
  if (threadIdx.x < 32) {
    const int dd = blockIdx.x * 32 + threadIdx.x;
    float a = b2[dd];
    #pragma unroll
    for (int s = 0; s < 8; ++s) a += red[s][threadIdx.x];
    emb[b * 1024 + dd] = a;
  }
}

__global__ void silu_k(const float* __restrict__ in, float* __restrict__ out, int n) {
  const int i = blockIdx.x * 256 + threadIdx.x;
  if (i < n) { const float v = in[i]; out[i] = v / (1.0f + __expf(-v)); }
}

__global__ void adaln_part(const float* __restrict__ se, const float* __restrict__ aw,
                           float* __restrict__ part) {
  const int j = blockIdx.x * 256 + threadIdx.x;  // 0..6143
  const int b = blockIdx.y, kz = blockIdx.z;
  float acc = 0.0f;
  for (int k = kz * 128; k < kz * 128 + 128; ++k) acc += se[b * 1024 + k] * aw[(long)k * 6144 + j];
  part[((long)kz * 2 + b) * 6144 + j] = acc;
}

__global__ void adaln_reduce(const float* __restrict__ part, const float* __restrict__ ab,
                             float* __restrict__ adaln) {
  const int j = blockIdx.x * 256 + threadIdx.x;
  const int b = blockIdx.y;
  float acc = ab[j];
  #pragma unroll
  for (int kz = 0; kz < 8; ++kz) acc += part[((long)kz * 2 + b) * 6144 + j];
  adaln[b * 6144 + j] = acc;
}

__global__ void build_mods(const float* __restrict__ sst, const float* __restrict__ adaln,
                           const float* __restrict__ fsst, const float* __restrict__ emb,
                           float* __restrict__ modAll, float* __restrict__ fmod) {
  const int i = blockIdx.x * 256 + threadIdx.x;
  if (i < 98304) {
    const int d = i & 1023;
    const int rest = i >> 10;
    const int slot = rest % 6;
    const int t2 = rest / 6;
    const int bb = t2 & 1, l = t2 >> 1;
    modAll[i] = sst[(long)(l * 6 + slot) * 1024 + d] + adaln[bb * 6144 + slot * 1024 + d];
  } else if (i < 98304 + 4096) {
    const int j = i - 98304;
    const int d = j & 1023;
    const int slot = (j >> 10) & 1;
    const int bb = j >> 11;
    fmod[j] = fsst[slot * 1024 + d] + emb[bb * 1024 + d];
  }
}

// ---------------------------------------------------------------- launch
extern "C" void kernel_launch(void* const* d_in, const int* in_sizes, int n_in,
                              void* d_out, int out_size, void* d_ws, size_t ws_size,
                              hipStream_t stream) {
  const float* inp_emb = (const float*)d_in[0];
  const float* amask  = (const float*)d_in[1];
  const float* tstep  = (const float*)d_in[2];
  const float* wpe    = (const float*)d_in[3];
  const float* ln1_g  = (const float*)d_in[4];
  const float* ln1_b  = (const float*)d_in[5];
  const float* attn_w = (const float*)d_in[6];
  const float* attn_b = (const float*)d_in[7];
  const float* projw  = (const float*)d_in[8];
  const float* projb  = (const float*)d_in[9];
  const float* ln2_g  = (const float*)d_in[10];
  const float* ln2_b  = (const float*)d_in[11];
  const float* fcw    = (const float*)d_in[12];
  const float* fcb    = (const float*)d_in[13];
  const float* pw2    = (const float*)d_in[14];
  const float* pb2    = (const float*)d_in[15];
  const float* sst    = (const float*)d_in[16];
  const float* te_w1  = (const float*)d_in[17];
  const float* te_b1  = (const float*)d_in[18];
  const float* te_w2  = (const float*)d_in[19];
  const float* te_b2  = (const float*)d_in[20];
  const float* ada_w  = (const float*)d_in[21];
  const float* ada_b  = (const float*)d_in[22];
  const float* lnf_g  = (const float*)d_in[23];
  const float* lnf_b  = (const float*)d_in[24];
  const float* fsst   = (const float*)d_in[25];
  const float* out_w  = (const float*)d_in[26];
  const float* out_b  = (const float*)d_in[27];
  float* out = (float*)d_out;
  (void)in_sizes; (void)n_in; (void)out_size; (void)ws_size;

  char* wsb = (char*)d_ws;
  size_t off = 0;
  auto alloc = [&](size_t bytes) -> void* {
    void* p = wsb + off;
    off += (bytes + 255) & ~(size_t)255;
    return p;
  };
  u16* wtA = (u16*)alloc(3072ll * 1024 * 2);
  u16* wtP = (u16*)alloc(1024ll * 1024 * 2);
  u16* wtF = (u16*)alloc(4096ll * 1024 * 2);
  u16* wtQ = (u16*)alloc(1024ll * 4096 * 2);
  u16* wtO = (u16*)alloc(1024ll * 1024 * 2);
  float* hs   = (float*)alloc(2048ll * 1024 * 4);
  float* qkv  = (float*)alloc(2048ll * 3072 * 4);
  u16*   ffb  = (u16*)qkv;                     // alias: FF activations reuse qkv space
  float* part = (float*)alloc(2ll * 2048 * 1024 * 4);  // split-K partials (also adaln partials)
  u16* xb = (u16*)alloc(2048ll * 1024 * 2);
  u16* qb = (u16*)alloc(2048ll * 1024 * 2);
  u16* kb = (u16*)alloc(2048ll * 1024 * 2);
  u16* vt = (u16*)alloc(2048ll * 1024 * 2);
  u16* ob = (u16*)alloc(2048ll * 1024 * 2);
  float* ct    = (float*)alloc(32768 * 4);
  float* st    = (float*)alloc(32768 * 4);
  float* tproj = (float*)alloc(2 * 512 * 4);
  float* h1    = (float*)alloc(2 * 1024 * 4);
  float* emb   = (float*)alloc(2 * 1024 * 4);
  float* se    = (float*)alloc(2 * 1024 * 4);
  float* adaln = (float*)alloc(2 * 6144 * 4);
  float* modAll = (float*)alloc(8ll * 2 * 6 * 1024 * 4);
  float* fmod   = (float*)alloc(2 * 2 * 1024 * 4);

  rope_tables<<<128, 256, 0, stream>>>(ct, st);
  init_hs<<<2048, 256, 0, stream>>>(inp_emb, wpe, hs);
  time_proj_k<<<dim3(2, 2), 256, 0, stream>>>(tstep, tproj);
  time_mlp1<<<dim3(32, 2), 256, 0, stream>>>(tproj, te_w1, te_b1, h1);
  time_mlp2<<<dim3(32, 2), 256, 0, stream>>>(h1, te_w2, te_b2, emb);
  silu_k<<<8, 256, 0, stream>>>(emb, se, 2048);
  adaln_part<<<dim3(24, 2, 8), 256, 0, stream>>>(se, ada_w, part);
  adaln_reduce<<<dim3(24, 2), 256, 0, stream>>>(part, ada_b, adaln);
  build_mods<<<400, 256, 0, stream>>>(sst, adaln, fsst, emb, modAll, fmod);
  transpose_k<<<dim3(16, 16), 256, 0, stream>>>(out_w, wtO, 1024, 1024);

  for (int l = 0; l < 8; ++l) {
    const float* ml = modAll + (long)l * 12288;
    transpose4_k<<<3072, 256, 0, stream>>>(attn_w + (long)l * 1024 * 3072, wtA,
                                           projw + (long)l * 1024 * 1024, wtP,
                                           fcw + (long)l * 1024 * 4096, wtF,
                                           pw2 + (long)l * 4096 * 1024, wtQ);

    ln_mod<<<2048, 256, 0, stream>>>(hs, ln1_g + l * 1024, ln1_b + l * 1024,
                                     ml + 0 * 1024, ml + 1 * 1024, 6144, xb);
    gemm_bt<128, EPI_F32, 1><<<dim3(16, 24), 256, 0, stream>>>(xb, wtA, attn_b + l * 3072,
                                                               qkv, nullptr, nullptr, nullptr, 2048, 3072, 1024);
    rope_split<<<2048, 256, 0, stream>>>(qkv, ct, st, qb, kb);
    v_transpose<<<dim3(16, 16, 2), 256, 0, stream>>>(qkv, vt);
    attn_k<<<dim3(16, 16, 2), 256, 0, stream>>>(qb, kb, vt, amask, ob);
    gemm_bt<64, EPI_GATE, 1><<<dim3(32, 8), 256, 0, stream>>>(ob, wtP, projb + l * 1024,
                                                              hs, nullptr, ml + 2 * 1024, hs, 2048, 1024, 1024);
    ln_mod<<<2048, 256, 0, stream>>>(hs, ln2_g + l * 1024, ln2_b + l * 1024,
                                     ml + 3 * 1024, ml + 4 * 1024, 6144, xb);
    gemm_bt<128, EPI_GELU, 1><<<dim3(16, 32), 256, 0, stream>>>(xb, wtF, fcb + l * 4096,
                                                                nullptr, ffb, nullptr, nullptr, 2048, 4096, 1024);
    gemm_bt<128, EPI_RAW, 2><<<dim3(16, 8, 2), 256, 0, stream>>>(ffb, wtQ, nullptr,
                                                                 part, nullptr, nullptr, nullptr, 2048, 1024, 4096);
    reduce_gate<<<2048, 256, 0, stream>>>(part, pb2 + l * 1024, ml + 5 * 1024, hs);
  }

  ln_mod<<<2048, 256, 0, stream>>>(hs, lnf_g, lnf_b, fmod + 0, fmod + 1024, 2048, xb);
  gemm_bt<64, EPI_F32, 1><<<dim3(32, 8), 256, 0, stream>>>(xb, wtO, out_b,
                                                           out, nullptr, nullptr, nullptr, 2048, 1024, 1024);
}

// Round 4
// 1825.731 us; speedup vs baseline: 1.6122x; 1.0688x over previous
//
#include <hip/hip_runtime.h>
#include <stdint.h>

typedef unsigned short u16;
typedef __attribute__((ext_vector_type(8))) short bf8_t;   // 8 x bf16
typedef __attribute__((ext_vector_type(4))) float f4_t;

#define DEV static __device__ __forceinline__
#define MFMA16(a, b, c) __builtin_amdgcn_mfma_f32_16x16x32_bf16((a), (b), (c), 0, 0, 0)
#define GLDS(gp, lp) __builtin_amdgcn_global_load_lds((const __attribute__((address_space(1))) void*)(gp), \
                                                      (__attribute__((address_space(3))) void*)(lp), 16, 0, 0)

DEV u16 f2bf(float f) {  // RNE float->bf16
  union { float f; uint32_t u; } x; x.f = f;
  uint32_t r = x.u + 0x7FFFu + ((x.u >> 16) & 1u);
  return (u16)(r >> 16);
}

// ---------------------------------------------------------------- transpose body (64x64, vectorized)
DEV void transpose_body(const float* __restrict__ W, u16* __restrict__ WT, int K, int N,
                        int n0, int k0, u16 (*tl)[66]) {
  const int t = threadIdx.x;
  const int tx = t & 15, ty = t >> 4;
  #pragma unroll
  for (int i = 0; i < 64; i += 16) {
    const float4 v = *(const float4*)&W[(long)(k0 + ty + i) * N + n0 + tx * 4];
    tl[tx * 4 + 0][ty + i] = f2bf(v.x);
    tl[tx * 4 + 1][ty + i] = f2bf(v.y);
    tl[tx * 4 + 2][ty + i] = f2bf(v.z);
    tl[tx * 4 + 3][ty + i] = f2bf(v.w);
  }
  __syncthreads();
  const int c = t & 15, r = t >> 4;
  #pragma unroll
  for (int i = 0; i < 64; i += 16) {
    const u16* p = &tl[r + i][c * 4];
    uint2 w;
    w.x = (uint32_t)p[0] | ((uint32_t)p[1] << 16);
    w.y = (uint32_t)p[2] | ((uint32_t)p[3] << 16);
    *(uint2*)&WT[(long)(n0 + r + i) * K + k0 + c * 4] = w;
  }
}

__global__ __launch_bounds__(256) void transpose_k(const float* __restrict__ W, u16* __restrict__ WT,
                                                   int K, int N) {
  __shared__ u16 tl[64][66];
  transpose_body(W, WT, K, N, blockIdx.x * 64, blockIdx.y * 64, tl);
}

__global__ __launch_bounds__(256)
void transpose4_k(const float* __restrict__ w0, u16* __restrict__ o0,   // attn_w  1024x3072
                  const float* __restrict__ w1, u16* __restrict__ o1,   // projw   1024x1024
                  const float* __restrict__ w2, u16* __restrict__ o2,   // fcw     1024x4096
                  const float* __restrict__ w3, u16* __restrict__ o3) { // pw2     4096x1024
  __shared__ u16 tl[64][66];
  int bid = blockIdx.x;
  const float* W; u16* O; int K, N, nbx;
  if (bid < 768)        {             W = w0; O = o0; K = 1024; N = 3072; nbx = 48; }
  else if (bid < 1024)  { bid -= 768; W = w1; O = o1; K = 1024; N = 1024; nbx = 16; }
  else if (bid < 2048)  { bid -= 1024; W = w2; O = o2; K = 1024; N = 4096; nbx = 64; }
  else                  { bid -= 2048; W = w3; O = o3; K = 4096; N = 1024; nbx = 16; }
  transpose_body(W, O, K, N, (bid % nbx) * 64, (bid / nbx) * 64, tl);
}

// ---------------------------------------------------------------- GEMM (dbuf LDS, 1 barrier/K-step)
enum { EPI_F32 = 0, EPI_GATE = 1, EPI_GELU = 2, EPI_RAW = 3 };

template <int BM, int EPI, int KS>
__global__ __launch_bounds__(256)
void gemm_bt(const u16* __restrict__ A, const u16* __restrict__ BT, const float* __restrict__ bias,
             float* outF, u16* outB, const float* gate, const float* res, int M, int N, int K) {
  constexpr int MI = BM / 32;
  __shared__ u16 sA[2][BM * 32];
  __shared__ u16 sB[2][128 * 32];
  const int tid = threadIdx.x, lane = tid & 63, wid = tid >> 6;
  const long rowBase = (long)blockIdx.x * BM;
  const long colBase = (long)blockIdx.y * 128;
  const int kz = (KS > 1) ? blockIdx.z : 0;
  const int kbeg = kz * (K / KS);
  const int wr = (wid >> 1) * (BM / 2), wc = (wid & 1) * 64;
  const int fr = lane & 15, kg = (lane >> 4) * 8;

  const f4_t zero = {0.0f, 0.0f, 0.0f, 0.0f};
  f4_t acc[MI][4];
  #pragma unroll
  for (int i = 0; i < MI; ++i)
    #pragma unroll
    for (int j = 0; j < 4; ++j) acc[i][j] = zero;

  const int sr = lane >> 2, scol = (lane & 3) * 8;
  const int c0 = wid * 2;
  const u16 *Ag0, *Ag1 = nullptr, *Bg0, *Bg1;
  int aoff0, aoff1 = 0, boff0, boff1;
  if constexpr (BM == 128) {
    Ag0 = A + (rowBase + c0 * 16 + sr) * (long)K + scol;
    Ag1 = A + (rowBase + c0 * 16 + 16 + sr) * (long)K + scol;
    aoff0 = (c0 * 16) * 32;
    aoff1 = (c0 * 16 + 16) * 32;
  } else {  // BM == 64
    Ag0 = A + (rowBase + wid * 16 + sr) * (long)K + scol;
    aoff0 = (wid * 16) * 32;
  }
  Bg0 = BT + (colBase + c0 * 16 + sr) * (long)K + scol;
  Bg1 = BT + (colBase + c0 * 16 + 16 + sr) * (long)K + scol;
  boff0 = (c0 * 16) * 32;
  boff1 = (c0 * 16 + 16) * 32;

  auto stage = [&](int buf, int k0) {
    GLDS(Ag0 + k0, &sA[buf][aoff0]);
    if constexpr (BM == 128) GLDS(Ag1 + k0, &sA[buf][aoff1]);
    GLDS(Bg0 + k0, &sB[buf][boff0]);
    GLDS(Bg1 + k0, &sB[buf][boff1]);
  };

  const int nk = (K / KS) / 32;
  stage(0, kbeg);
  __syncthreads();           // drain prologue stage
  int cur = 0;
  for (int t = 0; t < nk; ++t) {
    if (t + 1 < nk) stage(cur ^ 1, kbeg + (t + 1) * 32);   // issue next tile early
    bf8_t af[MI], bfv[4];
    #pragma unroll
    for (int m = 0; m < MI; ++m) af[m] = *(const bf8_t*)&sA[cur][(wr + m * 16 + fr) * 32 + kg];
    #pragma unroll
    for (int n = 0; n < 4; ++n) bfv[n] = *(const bf8_t*)&sB[cur][(wc + n * 16 + fr) * 32 + kg];
    #pragma unroll
    for (int m = 0; m < MI; ++m)
      #pragma unroll
      for (int n = 0; n < 4; ++n) acc[m][n] = MFMA16(af[m], bfv[n], acc[m][n]);
    __syncthreads();         // vmcnt(0)+barrier: next tile staged, readers done
    cur ^= 1;
  }

  const int r0 = (lane >> 4) * 4;
  #pragma unroll
  for (int m = 0; m < MI; ++m) {
    #pragma unroll
    for (int n = 0; n < 4; ++n) {
      const long col = colBase + wc + n * 16 + fr;
      const float bv = (EPI == EPI_RAW) ? 0.0f : bias[col];
      #pragma unroll
      for (int j = 0; j < 4; ++j) {
        const long row = rowBase + wr + m * 16 + r0 + j;
        float v = acc[m][n][j] + bv;
        if (EPI == EPI_F32) {
          outF[row * N + col] = v;
        } else if (EPI == EPI_RAW) {
          outF[((long)kz * M + row) * N + col] = v;
        } else if (EPI == EPI_GATE) {
          const int b = (int)(row >> 10);  // S = 1024
          const float g = gate[(long)b * 6144 + col];
          outF[row * N + col] = v * g + res[row * N + col];
        } else {  // tanh-GELU -> bf16
          const float t = 0.7978845608028654f * (v + 0.044715f * v * v * v);
          const float e = __expf(2.0f * t);
          const float th = 1.0f - 2.0f / (e + 1.0f);
          outB[row * N + col] = f2bf(0.5f * v * (1.0f + th));
        }
      }
    }
  }
}

// ---------------------------------------------------------------- LayerNorm + adaLN mod (wave per row)
__global__ __launch_bounds__(256)
void ln_mod(const float* __restrict__ h, const float* __restrict__ gamma, const float* __restrict__ beta,
            const float* shp, const float* scp, int bstride, u16* __restrict__ xb) {
  const int row = blockIdx.x * 4 + (threadIdx.x >> 6);
  const int lane = threadIdx.x & 63;
  const int b = row >> 10;
  const long base = (long)row * 1024;
  f4_t x[4];
  float s = 0.0f;
  #pragma unroll
  for (int j = 0; j < 4; ++j) {
    x[j] = *(const f4_t*)&h[base + j * 256 + lane * 4];
    s += x[j][0] + x[j][1] + x[j][2] + x[j][3];
  }
  #pragma unroll
  for (int o = 32; o > 0; o >>= 1) s += __shfl_xor(s, o);
  const float mean = s * 0.0009765625f;
  float vs = 0.0f;
  #pragma unroll
  for (int j = 0; j < 4; ++j)
    #pragma unroll
    for (int e = 0; e < 4; ++e) { const float d = x[j][e] - mean; vs += d * d; }
  #pragma unroll
  for (int o = 32; o > 0; o >>= 1) vs += __shfl_xor(vs, o);
  const float inv = rsqrtf(vs * 0.0009765625f + 1e-5f);
  #pragma unroll
  for (int j = 0; j < 4; ++j) {
    const int col = j * 256 + lane * 4;
    const f4_t gg = *(const f4_t*)&gamma[col];
    const f4_t bb = *(const f4_t*)&beta[col];
    const f4_t sh = *(const f4_t*)&shp[(long)b * bstride + col];
    const f4_t sc = *(const f4_t*)&scp[(long)b * bstride + col];
    union { u16 u[4]; uint2 v; } pk;
    #pragma unroll
    for (int e = 0; e < 4; ++e)
      pk.u[e] = f2bf(((x[j][e] - mean) * inv * gg[e] + bb[e]) * (1.0f + sc[e]) + sh[e]);
    *(uint2*)&xb[base + col] = pk.v;
  }
}

// ---------------------------------------------------------------- FC2 split-K reduce + gate + residual + next-LN
__global__ __launch_bounds__(256)
void reduce_gate_ln(const float* __restrict__ part, const float* __restrict__ bias,
                    const float* __restrict__ gate, float* __restrict__ hs,
                    const float* __restrict__ gamma, const float* __restrict__ beta,
                    const float* shp, const float* scp, int bstride, u16* __restrict__ xb) {
  const int row = blockIdx.x * 4 + (threadIdx.x >> 6);
  const int lane = threadIdx.x & 63;
  const int b = row >> 10;
  const long base = (long)row * 1024;
  f4_t v[4];
  float s = 0.0f;
  #pragma unroll
  for (int j = 0; j < 4; ++j) {
    const int col = j * 256 + lane * 4;
    const f4_t p = *(const f4_t*)&part[base + col];
    const f4_t q = *(const f4_t*)&part[2048ll * 1024 + base + col];
    const f4_t bv = *(const f4_t*)&bias[col];
    const f4_t gv = *(const f4_t*)&gate[(long)b * 6144 + col];
    const f4_t r = *(const f4_t*)&hs[base + col];
    f4_t o;
    #pragma unroll
    for (int e = 0; e < 4; ++e) o[e] = (p[e] + q[e] + bv[e]) * gv[e] + r[e];
    *(f4_t*)&hs[base + col] = o;
    v[j] = o;
    s += o[0] + o[1] + o[2] + o[3];
  }
  #pragma unroll
  for (int o = 32; o > 0; o >>= 1) s += __shfl_xor(s, o);
  const float mean = s * 0.0009765625f;
  float vs = 0.0f;
  #pragma unroll
  for (int j = 0; j < 4; ++j)
    #pragma unroll
    for (int e = 0; e < 4; ++e) { const float d = v[j][e] - mean; vs += d * d; }
  #pragma unroll
  for (int o = 32; o > 0; o >>= 1) vs += __shfl_xor(vs, o);
  const float inv = rsqrtf(vs * 0.0009765625f + 1e-5f);
  #pragma unroll
  for (int j = 0; j < 4; ++j) {
    const int col = j * 256 + lane * 4;
    const f4_t gg = *(const f4_t*)&gamma[col];
    const f4_t bb = *(const f4_t*)&beta[col];
    const f4_t sh = *(const f4_t*)&shp[(long)b * bstride + col];
    const f4_t sc = *(const f4_t*)&scp[(long)b * bstride + col];
    union { u16 u[4]; uint2 v; } pk;
    #pragma unroll
    for (int e = 0; e < 4; ++e)
      pk.u[e] = f2bf(((v[j][e] - mean) * inv * gg[e] + bb[e]) * (1.0f + sc[e]) + sh[e]);
    *(uint2*)&xb[base + col] = pk.v;
  }
}

// ---------------------------------------------------------------- RoPE split q/k -> bf16 [B][H][S][64]
__global__ __launch_bounds__(256)
void rope_split(const float* __restrict__ qkv, const float* __restrict__ ct, const float* __restrict__ st,
                u16* __restrict__ qb, u16* __restrict__ kb) {
  const int row = blockIdx.x;  // b*1024 + s
  const int b = row >> 10, s = row & 1023;
  const float* rp = qkv + (long)row * 3072;
  const int t = threadIdx.x;
  #pragma unroll
  for (int which = 0; which < 2; ++which) {
    const float* xp = rp + which * 1024;
    u16* op = which ? kb : qb;
    #pragma unroll
    for (int j = 0; j < 2; ++j) {
      const int p = t + j * 256;          // pair index 0..511
      const int h = p >> 5, i = p & 31;
      const float2 xx = *(const float2*)&xp[h * 64 + 2 * i];
      const float c = ct[s * 32 + i], sn = st[s * 32 + i];
      const long base = (((long)(b * 16 + h)) * 1024 + s) * 64 + 2 * i;
      const uint32_t w = (uint32_t)f2bf(xx.x * c - xx.y * sn) |
                         ((uint32_t)f2bf(xx.x * sn + xx.y * c) << 16);
      *(uint32_t*)&op[base] = w;
    }
  }
}

// ---------------------------------------------------------------- V transpose -> vt [bh][64][1024] bf16
__global__ __launch_bounds__(256)
void v_transpose(const float* __restrict__ qkv, u16* __restrict__ vt) {
  __shared__ u16 tl[64][66];
  const int s0 = blockIdx.x * 64;
  const int h = blockIdx.y, b = blockIdx.z;
  const int t = threadIdx.x;
  const int tx = t & 15, ty = t >> 4;
  #pragma unroll
  for (int i = 0; i < 64; i += 16) {
    const float4 v = *(const float4*)&qkv[(long)(b * 1024 + s0 + ty + i) * 3072 + 2048 + h * 64 + tx * 4];
    tl[tx * 4 + 0][ty + i] = f2bf(v.x);
    tl[tx * 4 + 1][ty + i] = f2bf(v.y);
    tl[tx * 4 + 2][ty + i] = f2bf(v.z);
    tl[tx * 4 + 3][ty + i] = f2bf(v.w);
  }
  __syncthreads();
  const int c = t & 15, r = t >> 4;
  #pragma unroll
  for (int i = 0; i < 64; i += 16) {
    const u16* p = &tl[r + i][c * 4];
    uint2 w;
    w.x = (uint32_t)p[0] | ((uint32_t)p[1] << 16);
    w.y = (uint32_t)p[2] | ((uint32_t)p[3] << 16);
    *(uint2*)&vt[((long)(b * 16 + h) * 64 + r + i) * 1024 + s0 + c * 4] = w;
  }
}

// ---------------------------------------------------------------- flash attention (1 wave / block)
DEV void attn_body(bf8_t (&kcur)[4][2], bf8_t (&knxt)[4][2], const bf8_t (&qf)[2],
                   f4_t (&oacc)[4], float& m, float& psum, int kc,
                   const u16* __restrict__ Kp, const u16* __restrict__ Vt,
                   const float* smadd, u16* myP, int fr, int g) {
  const f4_t zero = {0.0f, 0.0f, 0.0f, 0.0f};
  bf8_t vf[4][2];
  #pragma unroll
  for (int dt = 0; dt < 4; ++dt)
    #pragma unroll
    for (int ks = 0; ks < 2; ++ks)
      vf[dt][ks] = *(const bf8_t*)&Vt[(long)(dt * 16 + fr) * 1024 + kc + ks * 32 + g * 8];
  f4_t st[4];
  #pragma unroll
  for (int kt = 0; kt < 4; ++kt) {
    st[kt] = MFMA16(kcur[kt][0], qf[0], zero);
    st[kt] = MFMA16(kcur[kt][1], qf[1], st[kt]);
  }
  {  // prefetch next chunk's K
    const int kn = (kc + 64) & 1023;
    #pragma unroll
    for (int kt = 0; kt < 4; ++kt)
      #pragma unroll
      for (int dh = 0; dh < 2; ++dh)
        knxt[kt][dh] = *(const bf8_t*)&Kp[(long)(kn + kt * 16 + fr) * 64 + dh * 32 + g * 8];
  }
  float p[4][4];
  float cm = -3.402823466e38f;
  #pragma unroll
  for (int kt = 0; kt < 4; ++kt) {
    const f4_t ma = *(const f4_t*)&smadd[kc + kt * 16 + g * 4];
    #pragma unroll
    for (int j = 0; j < 4; ++j) {
      p[kt][j] = st[kt][j] * 0.125f + ma[j];
      cm = fmaxf(cm, p[kt][j]);
    }
  }
  cm = fmaxf(cm, __shfl_xor(cm, 16));
  cm = fmaxf(cm, __shfl_xor(cm, 32));
  const float nm = fmaxf(m, cm);
  const float sc = __expf(m - nm);
  m = nm;
  float ls = 0.0f;
  #pragma unroll
  for (int kt = 0; kt < 4; ++kt)
    #pragma unroll
    for (int j = 0; j < 4; ++j) {
      p[kt][j] = __expf(p[kt][j] - nm);
      ls += p[kt][j];
    }
  psum = psum * sc + ls;
  #pragma unroll
  for (int dt = 0; dt < 4; ++dt)
    #pragma unroll
    for (int j = 0; j < 4; ++j) oacc[dt][j] *= sc;
  #pragma unroll
  for (int kt = 0; kt < 4; ++kt) {
    const int kb = kt * 2 + (g >> 1);
    uint2 w;
    w.x = (uint32_t)f2bf(p[kt][0]) | ((uint32_t)f2bf(p[kt][1]) << 16);
    w.y = (uint32_t)f2bf(p[kt][2]) | ((uint32_t)f2bf(p[kt][3]) << 16);
    *(uint2*)&myP[(kb * 16 + fr) * 8 + (g & 1) * 4] = w;
  }
  bf8_t pa0 = *(const bf8_t*)&myP[(g * 16 + fr) * 8];
  bf8_t pa1 = *(const bf8_t*)&myP[((4 + g) * 16 + fr) * 8];
  #pragma unroll
  for (int dt = 0; dt < 4; ++dt) {
    oacc[dt] = MFMA16(vf[dt][0], pa0, oacc[dt]);
    oacc[dt] = MFMA16(vf[dt][1], pa1, oacc[dt]);
  }
}

__global__ __launch_bounds__(64)
void attn_k(const u16* __restrict__ qb, const u16* __restrict__ kb, const u16* __restrict__ vt,
            const float* __restrict__ amask, u16* __restrict__ ob) {
  __shared__ float smadd[1024];
  __shared__ u16 pl[1024];
  const int q0 = blockIdx.x * 16;
  const int h = blockIdx.y, b = blockIdx.z;
  const long bh = b * 16 + h;
  const int lane = threadIdx.x;
  const int fr = lane & 15, g = lane >> 4;

  #pragma unroll
  for (int i = 0; i < 4; ++i) {
    const int e = (lane + i * 64) * 4;
    const f4_t am = *(const f4_t*)&amask[b * 1024 + e];
    f4_t md;
    #pragma unroll
    for (int j = 0; j < 4; ++j) md[j] = (1.0f - am[j]) * -3.402823466e38f;
    *(f4_t*)&smadd[e] = md;
  }

  const u16* Q = qb + (bh * 1024 + q0) * 64;
  const u16* Kp = kb + bh * 1024 * 64;
  const u16* Vt = vt + bh * 64 * 1024;

  bf8_t qf[2];
  qf[0] = *(const bf8_t*)&Q[fr * 64 + g * 8];
  qf[1] = *(const bf8_t*)&Q[fr * 64 + 32 + g * 8];

  const f4_t zero = {0.0f, 0.0f, 0.0f, 0.0f};
  f4_t oacc[4];
  #pragma unroll
  for (int dt = 0; dt < 4; ++dt) oacc[dt] = zero;
  float m = -1e30f, psum = 0.0f;

  bf8_t kfA[4][2], kfB[4][2];
  #pragma unroll
  for (int kt = 0; kt < 4; ++kt)
    #pragma unroll
    for (int dh = 0; dh < 2; ++dh)
      kfA[kt][dh] = *(const bf8_t*)&Kp[(long)(kt * 16 + fr) * 64 + dh * 32 + g * 8];

  for (int kc = 0; kc < 1024; kc += 128) {
    attn_body(kfA, kfB, qf, oacc, m, psum, kc, Kp, Vt, smadd, pl, fr, g);
    attn_body(kfB, kfA, qf, oacc, m, psum, kc + 64, Kp, Vt, smadd, pl, fr, g);
  }

  float ts = psum + __shfl_xor(psum, 16);
  ts += __shfl_xor(ts, 32);
  const float inv = 1.0f / ts;
  const long qrow = (long)b * 1024 + q0 + fr;
  #pragma unroll
  for (int dt = 0; dt < 4; ++dt) {
    union { u16 u[4]; uint2 v; } pk;
    #pragma unroll
    for (int j = 0; j < 4; ++j) pk.u[j] = f2bf(oacc[dt][j] * inv);
    *(uint2*)&ob[qrow * 1024 + h * 64 + dt * 16 + g * 4] = pk.v;
  }
}

// ---------------------------------------------------------------- small kernels
__global__ void rope_tables(float* ct, float* st) {
  const int i = blockIdx.x * 256 + threadIdx.x;
  const int s = i >> 5, k = i & 31;
  const float freq = __expf(-9.210340371976184f * (float)(2 * k) / 64.0f);
  const float a = (float)s * freq;
  ct[i] = cosf(a);
  st[i] = sinf(a);
}

__global__ void init_hs(const float* __restrict__ e, const float* __restrict__ wpe, float* __restrict__ hs) {
  const long i = (long)blockIdx.x * 256 + threadIdx.x;
  float4 a = ((const float4*)e)[i];
  const float4 w = ((const float4*)wpe)[i & 262143];
  a.x += w.x; a.y += w.y; a.z += w.z; a.w += w.w;
  ((float4*)hs)[i] = a;
}

__global__ void time_proj_k(const float* __restrict__ ts, float* __restrict__ tproj) {
  const int j = blockIdx.x * 256 + threadIdx.x;  // 0..511
  const int b = blockIdx.y;
  const float tf = __expf(-9.210340371976184f * (float)(j & 255) / 256.0f);
  const float a = ts[b] * tf * 1000.0f;
  tproj[b * 512 + j] = (j < 256) ? cosf(a) : sinf(a);
}

__global__ __launch_bounds__(256)
void time_mlp1(const float* __restrict__ tproj, const float* __restrict__ w1,
               const float* __restrict__ b1, float* __restrict__ h1) {
  __shared__ float red[8][32];
  const int dl = threadIdx.x & 31, sl = threadIdx.x >> 5;
  const int d = blockIdx.x * 32 + dl, b = blockIdx.y;
  float acc = 0.0f;
  for (int j = sl * 64; j < sl * 64 + 64; ++j) acc += tproj[b * 512 + j] * w1[(long)j * 1024 + d];
  red[sl][dl] = acc;
  __syncthreads();
  if (threadIdx.x < 32) {
    const int dd = blockIdx.x * 32 + threadIdx.x;
    float a = b1[dd];
    #pragma unroll
    for (int s = 0; s < 8; ++s) a += red[s][threadIdx.x];
    h1[b * 1024 + dd] = a / (1.0f + __expf(-a));
  }
}

__global__ __launch_bounds__(256)
void time_mlp2(const float* __restrict__ h1, const float* __restrict__ w2,
               const float* __restrict__ b2, float* __restrict__ emb) {
  __shared__ float red[8][32];
  const int dl = threadIdx.x & 31, sl = threadIdx.x >> 5;
  const int d = blockIdx.x * 32 + dl, b = blockIdx.y;
  float acc = 0.0f;
  for (int j = sl * 128; j < sl * 128 + 128; ++j) acc += h1[b * 1024 + j] * w2[(long)j * 1024 + d];
  red[sl][dl] = acc;
  __syncthreads();
  if (threadIdx.x < 32) {
    const int dd = blockIdx.x * 32 + threadIdx.x;
    float a = b2[dd];
    #pragma unroll
    for (int s = 0; s < 8; ++s) a += red[s][threadIdx.x];
    emb[b * 1024 + dd] = a;
  }
}

__global__ void silu_k(const float* __restrict__ in, float* __restrict__ out, int n) {
  const int i = blockIdx.x * 256 + threadIdx.x;
  if (i < n) { const float v = in[i]; out[i] = v / (1.0f + __expf(-v)); }
}

__global__ void adaln_part(const float* __restrict__ se, const float* __restrict__ aw,
                           float* __restrict__ part) {
  const int j = blockIdx.x * 256 + threadIdx.x;  // 0..6143
  const int b = blockIdx.y, kz = blockIdx.z;
  float acc = 0.0f;
  for (int k = kz * 128; k < kz * 128 + 128; ++k) acc += se[b * 1024 + k] * aw[(long)k * 6144 + j];
  part[((long)kz * 2 + b) * 6144 + j] = acc;
}

__global__ void adaln_reduce(const float* __restrict__ part, const float* __restrict__ ab,
                             float* __restrict__ adaln) {
  const int j = blockIdx.x * 256 + threadIdx.x;
  const int b = blockIdx.y;
  float acc = ab[j];
  #pragma unroll
  for (int kz = 0; kz < 8; ++kz) acc += part[((long)kz * 2 + b) * 6144 + j];
  adaln[b * 6144 + j] = acc;
}

__global__ void build_mods(const float* __restrict__ sst, const float* __restrict__ adaln,
                           const float* __restrict__ fsst, const float* __restrict__ emb,
                           float* __restrict__ modAll, float* __restrict__ fmod) {
  const int i = blockIdx.x * 256 + threadIdx.x;
  if (i < 98304) {
    const int d = i & 1023;
    const int rest = i >> 10;
    const int slot = rest % 6;
    const int t2 = rest / 6;
    const int bb = t2 & 1, l = t2 >> 1;
    modAll[i] = sst[(long)(l * 6 + slot) * 1024 + d] + adaln[bb * 6144 + slot * 1024 + d];
  } else if (i < 98304 + 4096) {
    const int j = i - 98304;
    const int d = j & 1023;
    const int slot = (j >> 10) & 1;
    const int bb = j >> 11;
    fmod[j] = fsst[slot * 1024 + d] + emb[bb * 1024 + d];
  }
}

// ---------------------------------------------------------------- launch
extern "C" void kernel_launch(void* const* d_in, const int* in_sizes, int n_in,
                              void* d_out, int out_size, void* d_ws, size_t ws_size,
                              hipStream_t stream) {
  const float* inp_emb = (const float*)d_in[0];
  const float* amask  = (const float*)d_in[1];
  const float* tstep  = (const float*)d_in[2];
  const float* wpe    = (const float*)d_in[3];
  const float* ln1_g  = (const float*)d_in[4];
  const float* ln1_b  = (const float*)d_in[5];
  const float* attn_w = (const float*)d_in[6];
  const float* attn_b = (const float*)d_in[7];
  const float* projw  = (const float*)d_in[8];
  const float* projb  = (const float*)d_in[9];
  const float* ln2_g  = (const float*)d_in[10];
  const float* ln2_b  = (const float*)d_in[11];
  const float* fcw    = (const float*)d_in[12];
  const float* fcb    = (const float*)d_in[13];
  const float* pw2    = (const float*)d_in[14];
  const float* pb2    = (const float*)d_in[15];
  const float* sst    = (const float*)d_in[16];
  const float* te_w1  = (const float*)d_in[17];
  const float* te_b1  = (const float*)d_in[18];
  const float* te_w2  = (const float*)d_in[19];
  const float* te_b2  = (const float*)d_in[20];
  const float* ada_w  = (const float*)d_in[21];
  const float* ada_b  = (const float*)d_in[22];
  const float* lnf_g  = (const float*)d_in[23];
  const float* lnf_b  = (const float*)d_in[24];
  const float* fsst   = (const float*)d_in[25];
  const float* out_w  = (const float*)d_in[26];
  const float* out_b  = (const float*)d_in[27];
  float* out = (float*)d_out;
  (void)in_sizes; (void)n_in; (void)out_size; (void)ws_size;

  char* wsb = (char*)d_ws;
  size_t off = 0;
  auto alloc = [&](size_t bytes) -> void* {
    void* p = wsb + off;
    off += (bytes + 255) & ~(size_t)255;
    return p;
  };
  u16* wtA = (u16*)alloc(3072ll * 1024 * 2);
  u16* wtP = (u16*)alloc(1024ll * 1024 * 2);
  u16* wtF = (u16*)alloc(4096ll * 1024 * 2);
  u16* wtQ = (u16*)alloc(1024ll * 4096 * 2);
  u16* wtO = (u16*)alloc(1024ll * 1024 * 2);
  float* hs   = (float*)alloc(2048ll * 1024 * 4);
  float* qkv  = (float*)alloc(2048ll * 3072 * 4);
  u16*   ffb  = (u16*)qkv;                     // alias: FF activations reuse qkv space
  float* part = (float*)alloc(2ll * 2048 * 1024 * 4);  // split-K partials (also adaln partials)
  u16* xb = (u16*)alloc(2048ll * 1024 * 2);
  u16* qb = (u16*)alloc(2048ll * 1024 * 2);
  u16* kb = (u16*)alloc(2048ll * 1024 * 2);
  u16* vt = (u16*)alloc(2048ll * 1024 * 2);
  u16* ob = (u16*)alloc(2048ll * 1024 * 2);
  float* ct    = (float*)alloc(32768 * 4);
  float* st    = (float*)alloc(32768 * 4);
  float* tproj = (float*)alloc(2 * 512 * 4);
  float* h1    = (float*)alloc(2 * 1024 * 4);
  float* emb   = (float*)alloc(2 * 1024 * 4);
  float* se    = (float*)alloc(2 * 1024 * 4);
  float* adaln = (float*)alloc(2 * 6144 * 4);
  float* modAll = (float*)alloc(8ll * 2 * 6 * 1024 * 4);
  float* fmod   = (float*)alloc(2 * 2 * 1024 * 4);

  rope_tables<<<128, 256, 0, stream>>>(ct, st);
  init_hs<<<2048, 256, 0, stream>>>(inp_emb, wpe, hs);
  time_proj_k<<<dim3(2, 2), 256, 0, stream>>>(tstep, tproj);
  time_mlp1<<<dim3(32, 2), 256, 0, stream>>>(tproj, te_w1, te_b1, h1);
  time_mlp2<<<dim3(32, 2), 256, 0, stream>>>(h1, te_w2, te_b2, emb);
  silu_k<<<8, 256, 0, stream>>>(emb, se, 2048);
  adaln_part<<<dim3(24, 2, 8), 256, 0, stream>>>(se, ada_w, part);
  adaln_reduce<<<dim3(24, 2), 256, 0, stream>>>(part, ada_b, adaln);
  build_mods<<<400, 256, 0, stream>>>(sst, adaln, fsst, emb, modAll, fmod);
  transpose_k<<<dim3(16, 16), 256, 0, stream>>>(out_w, wtO, 1024, 1024);

  // layer-0 ln1 (later layers fuse ln1 into reduce_gate_ln)
  ln_mod<<<512, 256, 0, stream>>>(hs, ln1_g, ln1_b, modAll + 0 * 1024, modAll + 1 * 1024, 6144, xb);

  for (int l = 0; l < 8; ++l) {
    const float* ml = modAll + (long)l * 12288;
    transpose4_k<<<3072, 256, 0, stream>>>(attn_w + (long)l * 1024 * 3072, wtA,
                                           projw + (long)l * 1024 * 1024, wtP,
                                           fcw + (long)l * 1024 * 4096, wtF,
                                           pw2 + (long)l * 4096 * 1024, wtQ);

    gemm_bt<128, EPI_F32, 1><<<dim3(16, 24), 256, 0, stream>>>(xb, wtA, attn_b + l * 3072,
                                                               qkv, nullptr, nullptr, nullptr, 2048, 3072, 1024);
    rope_split<<<2048, 256, 0, stream>>>(qkv, ct, st, qb, kb);
    v_transpose<<<dim3(16, 16, 2), 256, 0, stream>>>(qkv, vt);
    attn_k<<<dim3(64, 16, 2), 64, 0, stream>>>(qb, kb, vt, amask, ob);
    gemm_bt<64, EPI_GATE, 1><<<dim3(32, 8), 256, 0, stream>>>(ob, wtP, projb + l * 1024,
                                                              hs, nullptr, ml + 2 * 1024, hs, 2048, 1024, 1024);
    ln_mod<<<512, 256, 0, stream>>>(hs, ln2_g + l * 1024, ln2_b + l * 1024,
                                    ml + 3 * 1024, ml + 4 * 1024, 6144, xb);
    gemm_bt<128, EPI_GELU, 1><<<dim3(16, 32), 256, 0, stream>>>(xb, wtF, fcb + l * 4096,
                                                                nullptr, ffb, nullptr, nullptr, 2048, 4096, 1024);
    gemm_bt<128, EPI_RAW, 2><<<dim3(16, 8, 2), 256, 0, stream>>>(ffb, wtQ, nullptr,
                                                                 part, nullptr, nullptr, nullptr, 2048, 1024, 4096);
    if (l < 7) {
      const float* mln = modAll + (long)(l + 1) * 12288;
      reduce_gate_ln<<<512, 256, 0, stream>>>(part, pb2 + l * 1024, ml + 5 * 1024, hs,
                                              ln1_g + (l + 1) * 1024, ln1_b + (l + 1) * 1024,
                                              mln + 0 * 1024, mln + 1 * 1024, 6144, xb);
    } else {
      reduce_gate_ln<<<512, 256, 0, stream>>>(part, pb2 + l * 1024, ml + 5 * 1024, hs,
                                              lnf_g, lnf_b, fmod + 0, fmod + 1024, 2048, xb);
    }
  }

  gemm_bt<64, EPI_F32, 1><<<dim3(32, 8), 256, 0, stream>>>(xb, wtO, out_b,
                                                           out, nullptr, nullptr, nullptr, 2048, 1024, 1024);
}